// Round 1
// baseline (3445.955 us; speedup 1.0000x reference)
//
#include <hip/hip_runtime.h>
#include <hip/hip_bf16.h>
#include <cstddef>

#define H 16
#define DN 128
#define DR 64
#define DV 128
#define QLR 1536
#define KVLR 512
#define HID 2048
#define SLEN 2048
#define EPS 1e-6f
#define SCALE 0.08838834764831845f   /* 1/sqrt(128) */

// ---------------- tiled fp32 GEMM: C[M,N] = A[M,K](lda) @ B[K,N] ----------------
// requires M%64==0, N%64==0, K%16==0; 256 threads; each thread 4x4 outputs.
__global__ __launch_bounds__(256) void gemm_f32(
    const float* __restrict__ A, const float* __restrict__ B, float* __restrict__ C,
    int M, int N, int K, int lda)
{
    __shared__ float As[16][68];   // transposed: As[k][m], padded for alignment
    __shared__ float Bs[16][68];   // Bs[k][n]
    const int n0 = blockIdx.x * 64, m0 = blockIdx.y * 64;
    const int tid = threadIdx.x;
    const int tx = tid & 15, ty = tid >> 4;
    float acc[4][4] = {};
    for (int k0 = 0; k0 < K; k0 += 16) {
        {
            int row = tid >> 2;          // m: 0..63
            int c4  = (tid & 3) * 4;     // k offset
            float4 v = *reinterpret_cast<const float4*>(A + (size_t)(m0 + row) * lda + k0 + c4);
            As[c4 + 0][row] = v.x; As[c4 + 1][row] = v.y;
            As[c4 + 2][row] = v.z; As[c4 + 3][row] = v.w;
        }
        {
            int row = tid >> 4;          // k: 0..15
            int c4  = (tid & 15) * 4;    // n offset
            float4 v = *reinterpret_cast<const float4*>(B + (size_t)(k0 + row) * N + n0 + c4);
            *reinterpret_cast<float4*>(&Bs[row][c4]) = v;
        }
        __syncthreads();
        #pragma unroll
        for (int kk = 0; kk < 16; ++kk) {
            float4 a = *reinterpret_cast<const float4*>(&As[kk][ty * 4]);
            float4 b = *reinterpret_cast<const float4*>(&Bs[kk][tx * 4]);
            float av[4] = {a.x, a.y, a.z, a.w}, bv[4] = {b.x, b.y, b.z, b.w};
            #pragma unroll
            for (int i = 0; i < 4; ++i)
                #pragma unroll
                for (int j = 0; j < 4; ++j) acc[i][j] += av[i] * bv[j];
        }
        __syncthreads();
    }
    #pragma unroll
    for (int i = 0; i < 4; ++i) {
        float4 v = make_float4(acc[i][0], acc[i][1], acc[i][2], acc[i][3]);
        *reinterpret_cast<float4*>(C + (size_t)(m0 + ty * 4 + i) * N + n0 + tx * 4) = v;
    }
}

// ---------------- RMSNorm (in place): rows of length D within stride-rowStride matrix
__global__ __launch_bounds__(256) void rmsnorm_rows(
    float* __restrict__ x, const float* __restrict__ w, int rowStride, int D)
{
    const int row = blockIdx.x;
    float* p = x + (size_t)row * rowStride;
    const int tid = threadIdx.x;
    float ss = 0.f;
    for (int i = tid; i < D; i += 256) { float v = p[i]; ss += v * v; }
    __shared__ float wsum[4];
    int lane = tid & 63, wv = tid >> 6;
    #pragma unroll
    for (int off = 32; off; off >>= 1) ss += __shfl_down(ss, off);
    if (lane == 0) wsum[wv] = ss;
    __syncthreads();
    if (tid == 0) {
        float t = wsum[0] + wsum[1] + wsum[2] + wsum[3];
        wsum[0] = rsqrtf(t / (float)D + EPS);
    }
    __syncthreads();
    float sc = wsum[0];
    for (int i = tid; i < D; i += 256) p[i] = p[i] * sc * w[i];
}

// ---------------- RoPE: q (in-place, [S][H][192], last 64 of each head) + k_rot [S][64]
__global__ __launch_bounds__(256) void rope_kernel(
    float* __restrict__ q, const float* __restrict__ ckv, float* __restrict__ krot)
{
    const int s = blockIdx.x;
    const int tid = threadIdx.x;
    float vals[2][2], cs[2], sn[2];
    int hh[2], ii[2];
    #pragma unroll
    for (int itr = 0; itr < 2; ++itr) {
        int p = tid + itr * 256;           // 0..511 = H*32 pairs
        int h = p >> 5, i = p & 31;
        hh[itr] = h; ii[itr] = i;
        float inv = powf(10000.0f, -(float)i / 32.0f);
        float ang = (float)s * inv;
        cs[itr] = cosf(ang); sn[itr] = sinf(ang);
        const float* base = q + ((size_t)s * H + h) * 192 + 128;
        vals[itr][0] = base[2 * i]; vals[itr][1] = base[2 * i + 1];
    }
    __syncthreads();
    #pragma unroll
    for (int itr = 0; itr < 2; ++itr) {
        float* base = q + ((size_t)s * H + hh[itr]) * 192 + 128;
        base[ii[itr]]      = vals[itr][0] * cs[itr] - vals[itr][1] * sn[itr];
        base[32 + ii[itr]] = vals[itr][1] * cs[itr] + vals[itr][0] * sn[itr];
    }
    if (tid < 32) {
        int i = tid;
        float inv = powf(10000.0f, -(float)i / 32.0f);
        float ang = (float)s * inv;
        float c = cosf(ang), sN = sinf(ang);
        float e = ckv[(size_t)s * 576 + 512 + 2 * i];
        float o = ckv[(size_t)s * 576 + 512 + 2 * i + 1];
        krot[(size_t)s * 64 + i]      = e * c - o * sN;
        krot[(size_t)s * 64 + 32 + i] = o * c + e * sN;
    }
}

// ---------------- flash-style causal attention ----------------
// grid (64 qblocks, 16 heads); 256 threads; QB=32 query rows, KB=16 keys/iter.
__global__ __launch_bounds__(256) void attn_kernel(
    const float* __restrict__ q,    // [S][H][192]  (rope applied)
    const float* __restrict__ kv,   // [S][H][256]  (k_nope | v)
    const float* __restrict__ krot, // [S][64]      (shared across heads)
    float* __restrict__ out)        // [S][H*128]
{
    const int h  = blockIdx.y;
    const int qb = blockIdx.x;
    const int s0 = qb * 32;
    const int tid = threadIdx.x;

    __shared__ float Qs[32][192];
    __shared__ float Ks[16][193];
    __shared__ float Vs[16][128];
    __shared__ float Sc[32][17];
    __shared__ float mrow[32], lrow[32], frow[32];

    float acc[16] = {};

    for (int idx = tid; idx < 32 * 192; idx += 256) {
        int r = idx / 192, d = idx % 192;
        Qs[r][d] = q[((size_t)(s0 + r) * H + h) * 192 + d];
    }
    if (tid < 32) { mrow[tid] = -1e30f; lrow[tid] = 0.f; }
    __syncthreads();

    const int nkb = 2 * qb + 2;   // key blocks of 16 covering keys 0..s0+31
    for (int kb = 0; kb < nkb; ++kb) {
        // load K (16x192) and V (16x128)
        for (int idx = tid; idx < 16 * 192; idx += 256) {
            int t = idx / 192, d = idx % 192;
            int gk = kb * 16 + t;
            float v = (d < 128) ? kv[((size_t)gk * H + h) * 256 + d]
                                : krot[(size_t)gk * 64 + (d - 128)];
            Ks[t][d] = v;
        }
        for (int idx = tid; idx < 16 * 128; idx += 256) {
            int t = idx / 128, c = idx % 128;
            int gk = kb * 16 + t;
            Vs[t][c] = kv[((size_t)gk * H + h) * 256 + 128 + c];
        }
        __syncthreads();

        // scores: 32x16, two per thread
        {
            int r  = tid >> 3;
            int t0 = (tid & 7) * 2;
            float d0 = 0.f, d1 = 0.f;
            for (int k = 0; k < 192; ++k) {
                float qv = Qs[r][k];
                d0 += qv * Ks[t0][k];
                d1 += qv * Ks[t0 + 1][k];
            }
            int gs = s0 + r;
            int g0 = kb * 16 + t0;
            Sc[r][t0]     = (g0     <= gs) ? d0 * SCALE : -1e30f;
            Sc[r][t0 + 1] = (g0 + 1 <= gs) ? d1 * SCALE : -1e30f;
        }
        __syncthreads();

        // online softmax update, one thread per row
        if (tid < 32) {
            int r = tid;
            float m0 = mrow[r], mx = m0;
            #pragma unroll
            for (int t = 0; t < 16; ++t) mx = fmaxf(mx, Sc[r][t]);
            float f = __expf(m0 - mx);
            float sum = 0.f;
            #pragma unroll
            for (int t = 0; t < 16; ++t) {
                float pz = __expf(Sc[r][t] - mx);
                Sc[r][t] = pz; sum += pz;
            }
            lrow[r] = lrow[r] * f + sum;
            mrow[r] = mx;
            frow[r] = f;
        }
        __syncthreads();

        // PV: thread owns (r, 16 cols)
        {
            int r  = tid >> 3;
            int c0 = (tid & 7) * 16;
            float f = frow[r];
            #pragma unroll
            for (int j = 0; j < 16; ++j) acc[j] *= f;
            for (int t = 0; t < 16; ++t) {
                float pz = Sc[r][t];
                #pragma unroll
                for (int j = 0; j < 16; ++j) acc[j] += pz * Vs[t][c0 + j];
            }
        }
        __syncthreads();
    }

    {
        int r  = tid >> 3;
        int c0 = (tid & 7) * 16;
        float inv_l = 1.f / lrow[r];
        #pragma unroll
        for (int j = 0; j < 16; ++j)
            out[(size_t)(s0 + r) * 2048 + h * 128 + c0 + j] = acc[j] * inv_l;
    }
}

extern "C" void kernel_launch(void* const* d_in, const int* in_sizes, int n_in,
                              void* d_out, int out_size, void* d_ws, size_t ws_size,
                              hipStream_t stream)
{
    (void)in_sizes; (void)n_in; (void)out_size; (void)ws_size;
    const float* x         = (const float*)d_in[0];
    const float* Wq_down   = (const float*)d_in[1];
    const float* q_norm_w  = (const float*)d_in[2];
    const float* Wq_up     = (const float*)d_in[3];
    const float* Wkv_down  = (const float*)d_in[4];
    const float* kv_norm_w = (const float*)d_in[5];
    const float* Wkv_up    = (const float*)d_in[6];
    const float* Wo        = (const float*)d_in[7];
    float* out = (float*)d_out;

    float* ws     = (float*)d_ws;
    float* q_down = ws;                               // 2048*1536
    float* qbuf   = q_down + (size_t)SLEN * QLR;      // 2048*3072  [s][h][192]
    float* ckv    = qbuf   + (size_t)SLEN * H * 192;  // 2048*576
    float* kvbuf  = ckv    + (size_t)SLEN * 576;      // 2048*4096  [s][h][256]
    float* krot   = kvbuf  + (size_t)SLEN * H * 256;  // 2048*64
    float* attout = krot   + (size_t)SLEN * 64;       // 2048*2048

    dim3 blk(256);
    // 1) q_down = x @ Wq_down            [2048,2048]x[2048,1536]
    gemm_f32<<<dim3(QLR / 64, SLEN / 64), blk, 0, stream>>>(x, Wq_down, q_down, SLEN, QLR, HID, HID);
    // 2) rmsnorm(q_down)
    rmsnorm_rows<<<SLEN, blk, 0, stream>>>(q_down, q_norm_w, QLR, QLR);
    // 3) q = q_down @ Wq_up              [2048,1536]x[1536,3072]
    gemm_f32<<<dim3((H * 192) / 64, SLEN / 64), blk, 0, stream>>>(q_down, Wq_up, qbuf, SLEN, H * 192, QLR, QLR);
    // 4) ckv = x @ Wkv_down              [2048,2048]x[2048,576]
    gemm_f32<<<dim3(576 / 64, SLEN / 64), blk, 0, stream>>>(x, Wkv_down, ckv, SLEN, 576, HID, HID);
    // 5) rmsnorm(c)  (first 512 cols of ckv, in place)
    rmsnorm_rows<<<SLEN, blk, 0, stream>>>(ckv, kv_norm_w, 576, KVLR);
    // 6) kv = c @ Wkv_up                 [2048,512(lda 576)]x[512,4096]
    gemm_f32<<<dim3((H * 256) / 64, SLEN / 64), blk, 0, stream>>>(ckv, Wkv_up, kvbuf, SLEN, H * 256, KVLR, 576);
    // 7) RoPE on q (in place) + k_rot
    rope_kernel<<<SLEN, blk, 0, stream>>>(qbuf, ckv, krot);
    // 8) causal attention -> attout [s][h*128+d]
    attn_kernel<<<dim3(SLEN / 32, H), blk, 0, stream>>>(qbuf, kvbuf, krot, attout);
    // 9) out = attout @ Wo               [2048,2048]x[2048,2048]
    gemm_f32<<<dim3(HID / 64, SLEN / 64), blk, 0, stream>>>(attout, Wo, out, SLEN, HID, HID, HID);
}

// Round 2
// 1384.822 us; speedup vs baseline: 2.4884x; 2.4884x over previous
//
#include <hip/hip_runtime.h>
#include <hip/hip_bf16.h>
#include <cstddef>

#define H 16
#define DN 128
#define DR 64
#define DV 128
#define QLR 1536
#define KVLR 512
#define HID 2048
#define SLEN 2048
#define EPS 1e-6f
#define SCALE 0.08838834764831845f   /* 1/sqrt(128) */

typedef __attribute__((ext_vector_type(8))) short short8;
typedef __attribute__((ext_vector_type(4))) float f32x4;
typedef unsigned short u16;

__device__ inline u16 f2bf(float f) {
    __hip_bfloat16 h = __float2bfloat16(f);
    return __builtin_bit_cast(u16, h);
}

// ---------------- tiled fp32 GEMM: C[M,N] = A[M,K](lda) @ B[K,N] ----------------
__global__ __launch_bounds__(256) void gemm_f32(
    const float* __restrict__ A, const float* __restrict__ B, float* __restrict__ C,
    int M, int N, int K, int lda)
{
    __shared__ float As[16][68];
    __shared__ float Bs[16][68];
    const int n0 = blockIdx.x * 64, m0 = blockIdx.y * 64;
    const int tid = threadIdx.x;
    const int tx = tid & 15, ty = tid >> 4;
    float acc[4][4] = {};
    for (int k0 = 0; k0 < K; k0 += 16) {
        {
            int row = tid >> 2;
            int c4  = (tid & 3) * 4;
            float4 v = *reinterpret_cast<const float4*>(A + (size_t)(m0 + row) * lda + k0 + c4);
            As[c4 + 0][row] = v.x; As[c4 + 1][row] = v.y;
            As[c4 + 2][row] = v.z; As[c4 + 3][row] = v.w;
        }
        {
            int row = tid >> 4;
            int c4  = (tid & 15) * 4;
            float4 v = *reinterpret_cast<const float4*>(B + (size_t)(k0 + row) * N + n0 + c4);
            *reinterpret_cast<float4*>(&Bs[row][c4]) = v;
        }
        __syncthreads();
        #pragma unroll
        for (int kk = 0; kk < 16; ++kk) {
            float4 a = *reinterpret_cast<const float4*>(&As[kk][ty * 4]);
            float4 b = *reinterpret_cast<const float4*>(&Bs[kk][tx * 4]);
            float av[4] = {a.x, a.y, a.z, a.w}, bv[4] = {b.x, b.y, b.z, b.w};
            #pragma unroll
            for (int i = 0; i < 4; ++i)
                #pragma unroll
                for (int j = 0; j < 4; ++j) acc[i][j] += av[i] * bv[j];
        }
        __syncthreads();
    }
    #pragma unroll
    for (int i = 0; i < 4; ++i) {
        float4 v = make_float4(acc[i][0], acc[i][1], acc[i][2], acc[i][3]);
        *reinterpret_cast<float4*>(C + (size_t)(m0 + ty * 4 + i) * N + n0 + tx * 4) = v;
    }
}

// same GEMM but stores bf16
__global__ __launch_bounds__(256) void gemm_f32_bf16out(
    const float* __restrict__ A, const float* __restrict__ B, u16* __restrict__ C,
    int M, int N, int K, int lda)
{
    __shared__ float As[16][68];
    __shared__ float Bs[16][68];
    const int n0 = blockIdx.x * 64, m0 = blockIdx.y * 64;
    const int tid = threadIdx.x;
    const int tx = tid & 15, ty = tid >> 4;
    float acc[4][4] = {};
    for (int k0 = 0; k0 < K; k0 += 16) {
        {
            int row = tid >> 2;
            int c4  = (tid & 3) * 4;
            float4 v = *reinterpret_cast<const float4*>(A + (size_t)(m0 + row) * lda + k0 + c4);
            As[c4 + 0][row] = v.x; As[c4 + 1][row] = v.y;
            As[c4 + 2][row] = v.z; As[c4 + 3][row] = v.w;
        }
        {
            int row = tid >> 4;
            int c4  = (tid & 15) * 4;
            float4 v = *reinterpret_cast<const float4*>(B + (size_t)(k0 + row) * N + n0 + c4);
            *reinterpret_cast<float4*>(&Bs[row][c4]) = v;
        }
        __syncthreads();
        #pragma unroll
        for (int kk = 0; kk < 16; ++kk) {
            float4 a = *reinterpret_cast<const float4*>(&As[kk][ty * 4]);
            float4 b = *reinterpret_cast<const float4*>(&Bs[kk][tx * 4]);
            float av[4] = {a.x, a.y, a.z, a.w}, bv[4] = {b.x, b.y, b.z, b.w};
            #pragma unroll
            for (int i = 0; i < 4; ++i)
                #pragma unroll
                for (int j = 0; j < 4; ++j) acc[i][j] += av[i] * bv[j];
        }
        __syncthreads();
    }
    #pragma unroll
    for (int i = 0; i < 4; ++i) {
        uint2 pk;
        pk.x = (unsigned)f2bf(acc[i][0]) | ((unsigned)f2bf(acc[i][1]) << 16);
        pk.y = (unsigned)f2bf(acc[i][2]) | ((unsigned)f2bf(acc[i][3]) << 16);
        *reinterpret_cast<uint2*>(C + (size_t)(m0 + ty * 4 + i) * N + n0 + tx * 4) = pk;
    }
}

// ---------------- RMSNorm (in place) ----------------
__global__ __launch_bounds__(256) void rmsnorm_rows(
    float* __restrict__ x, const float* __restrict__ w, int rowStride, int D)
{
    const int row = blockIdx.x;
    float* p = x + (size_t)row * rowStride;
    const int tid = threadIdx.x;
    float ss = 0.f;
    for (int i = tid; i < D; i += 256) { float v = p[i]; ss += v * v; }
    __shared__ float wsum[4];
    int lane = tid & 63, wv = tid >> 6;
    #pragma unroll
    for (int off = 32; off; off >>= 1) ss += __shfl_down(ss, off);
    if (lane == 0) wsum[wv] = ss;
    __syncthreads();
    if (tid == 0) {
        float t = wsum[0] + wsum[1] + wsum[2] + wsum[3];
        wsum[0] = rsqrtf(t / (float)D + EPS);
    }
    __syncthreads();
    float sc = wsum[0];
    for (int i = tid; i < D; i += 256) p[i] = p[i] * sc * w[i];
}

// ---------------- RoPE + cast to bf16 ----------------
// q fp32 [S][H][192] -> qbf bf16 (rope applied to last 64 of each head)
// ckv fp32 [S][576]  -> krot bf16 [S][64]
__global__ __launch_bounds__(256) void rope_cast(
    const float* __restrict__ q, const float* __restrict__ ckv,
    u16* __restrict__ qbf, u16* __restrict__ krot)
{
    const int s = blockIdx.x;
    const int tid = threadIdx.x;
    __shared__ float cs[32], sn[32];
    if (tid < 32) {
        float inv = powf(10000.0f, -(float)tid / 32.0f);
        float ang = (float)s * inv;
        cs[tid] = cosf(ang); sn[tid] = sinf(ang);
    }
    __syncthreads();
    const float* qrow = q + (size_t)s * 3072;
    u16* orow = qbf + (size_t)s * 3072;
    for (int idx = tid; idx < 3072; idx += 256) {
        int d = idx % 192; int base = idx - d;
        float val;
        if (d < 128) val = qrow[idx];
        else {
            int i = (d - 128) & 31;
            float e = qrow[base + 128 + 2 * i], o = qrow[base + 129 + 2 * i];
            val = (d < 160) ? (e * cs[i] - o * sn[i]) : (o * cs[i] + e * sn[i]);
        }
        orow[idx] = f2bf(val);
    }
    if (tid < 32) {
        int i = tid;
        float e = ckv[(size_t)s * 576 + 512 + 2 * i];
        float o = ckv[(size_t)s * 576 + 512 + 2 * i + 1];
        krot[(size_t)s * 64 + i]      = f2bf(e * cs[i] - o * sn[i]);
        krot[(size_t)s * 64 + 32 + i] = f2bf(o * cs[i] + e * sn[i]);
    }
}

// ---------------- MFMA flash attention ----------------
// grid (32 qblocks of 64 rows, 16 heads); 256 threads = 4 waves; KB=32 keys/iter.
__global__ __launch_bounds__(256) void attn_mfma(
    const u16* __restrict__ qbf,   // [S][H][192]
    const u16* __restrict__ kvbf,  // [S][H][256]  (k_nope | v)
    const u16* __restrict__ krot,  // [S][64]
    float* __restrict__ out)       // [S][2048]
{
    const int h = blockIdx.y, qb = blockIdx.x, s0 = qb * 64;
    const int tid = threadIdx.x, lane = tid & 63, w = tid >> 6;

    __shared__ u16 Qs[64][200];   // pad: stride 400B (16B aligned, 2-way banks)
    __shared__ u16 Ks[32][200];
    __shared__ u16 Vt[128][40];   // V transposed: Vt[dim][key]
    __shared__ u16 Ps[64][40];    // P tile bf16

    // stage Q: 64 rows x 192, short8 chunks (64*24=1536 chunks)
    for (int it = 0; it < 6; ++it) {
        int c = it * 256 + tid;
        int r = c / 24, d0 = (c % 24) * 8;
        short8 v = *reinterpret_cast<const short8*>(qbf + ((size_t)(s0 + r) * H + h) * 192 + d0);
        *reinterpret_cast<short8*>(&Qs[r][d0]) = v;
    }

    float m_run[4] = {-1e30f, -1e30f, -1e30f, -1e30f};
    float l_run[4] = {0.f, 0.f, 0.f, 0.f};
    f32x4 acc_o[8];
    #pragma unroll
    for (int i = 0; i < 8; ++i) acc_o[i] = (f32x4){0.f, 0.f, 0.f, 0.f};

    const int colk = lane & 15;
    const int g8 = (lane >> 4) * 8;
    const int nkt = 2 * qb + 2;

    for (int kb = 0; kb < nkt; ++kb) {
        __syncthreads();   // prev iter done reading Ks/Vt (covers Qs at kb==0 via next barrier)
        // stage K tile: 32 keys x 192 (k_nope | k_rot)
        for (int it = 0; it < 3; ++it) {
            int c = it * 256 + tid;
            int t = c / 24, d0 = (c % 24) * 8;
            int gk = kb * 32 + t;
            const u16* src = (d0 < 128)
                ? kvbf + ((size_t)gk * H + h) * 256 + d0
                : krot + (size_t)gk * 64 + (d0 - 128);
            *reinterpret_cast<short8*>(&Ks[t][d0]) = *reinterpret_cast<const short8*>(src);
        }
        // stage V transposed: 32 keys x 128 dims
        for (int it = 0; it < 16; ++it) {
            int idx = it * 256 + tid;
            int t = idx >> 7, c = idx & 127;
            Vt[c][t] = kvbf[((size_t)(kb * 32 + t) * H + h) * 256 + 128 + c];
        }
        __syncthreads();

        // QK^T: wave w owns rows w*16..w*16+15; 2 col-tiles x 6 k-steps
        f32x4 sacc[2];
        sacc[0] = (f32x4){0.f, 0.f, 0.f, 0.f};
        sacc[1] = (f32x4){0.f, 0.f, 0.f, 0.f};
        const int arow = w * 16 + colk;
        #pragma unroll
        for (int ks = 0; ks < 6; ++ks) {
            short8 a  = *reinterpret_cast<const short8*>(&Qs[arow][ks * 32 + g8]);
            short8 b0 = *reinterpret_cast<const short8*>(&Ks[colk][ks * 32 + g8]);
            short8 b1 = *reinterpret_cast<const short8*>(&Ks[16 + colk][ks * 32 + g8]);
            sacc[0] = __builtin_amdgcn_mfma_f32_16x16x32_bf16(a, b0, sacc[0], 0, 0, 0);
            sacc[1] = __builtin_amdgcn_mfma_f32_16x16x32_bf16(a, b1, sacc[1], 0, 0, 0);
        }

        // in-register online softmax (row = 4*(lane>>4)+reg across 16 lanes of group)
        const int key0 = kb * 32 + colk, key1 = key0 + 16;
        const int rbase = s0 + w * 16 + (lane >> 4) * 4;
        #pragma unroll
        for (int reg = 0; reg < 4; ++reg) {
            int qg = rbase + reg;
            float sv0 = (key0 <= qg) ? sacc[0][reg] * SCALE : -1e30f;
            float sv1 = (key1 <= qg) ? sacc[1][reg] * SCALE : -1e30f;
            float mx = fmaxf(sv0, sv1);
            mx = fmaxf(mx, __shfl_xor(mx, 1));
            mx = fmaxf(mx, __shfl_xor(mx, 2));
            mx = fmaxf(mx, __shfl_xor(mx, 4));
            mx = fmaxf(mx, __shfl_xor(mx, 8));
            float mnew = fmaxf(m_run[reg], mx);
            float f = __expf(m_run[reg] - mnew);
            m_run[reg] = mnew;
            float p0 = __expf(sv0 - mnew);
            float p1 = __expf(sv1 - mnew);
            float rs = p0 + p1;
            rs += __shfl_xor(rs, 1);
            rs += __shfl_xor(rs, 2);
            rs += __shfl_xor(rs, 4);
            rs += __shfl_xor(rs, 8);
            l_run[reg] = l_run[reg] * f + rs;
            #pragma unroll
            for (int ct = 0; ct < 8; ++ct) acc_o[ct][reg] *= f;
            int prow = w * 16 + (lane >> 4) * 4 + reg;
            Ps[prow][colk]      = f2bf(p0);
            Ps[prow][16 + colk] = f2bf(p1);
        }
        __syncthreads();   // order Ps writes before b128 reads

        // PV: O[16x128] += P[16x32] @ V[32x128]
        short8 pa = *reinterpret_cast<const short8*>(&Ps[w * 16 + colk][g8]);
        #pragma unroll
        for (int ct = 0; ct < 8; ++ct) {
            short8 vb = *reinterpret_cast<const short8*>(&Vt[ct * 16 + colk][g8]);
            acc_o[ct] = __builtin_amdgcn_mfma_f32_16x16x32_bf16(pa, vb, acc_o[ct], 0, 0, 0);
        }
    }

    // epilogue: normalize and store fp32
    #pragma unroll
    for (int reg = 0; reg < 4; ++reg) {
        float invl = 1.0f / l_run[reg];
        int row = s0 + w * 16 + (lane >> 4) * 4 + reg;
        #pragma unroll
        for (int ct = 0; ct < 8; ++ct)
            out[(size_t)row * 2048 + h * 128 + ct * 16 + colk] = acc_o[ct][reg] * invl;
    }
}

extern "C" void kernel_launch(void* const* d_in, const int* in_sizes, int n_in,
                              void* d_out, int out_size, void* d_ws, size_t ws_size,
                              hipStream_t stream)
{
    (void)in_sizes; (void)n_in; (void)out_size; (void)ws_size;
    const float* x         = (const float*)d_in[0];
    const float* Wq_down   = (const float*)d_in[1];
    const float* q_norm_w  = (const float*)d_in[2];
    const float* Wq_up     = (const float*)d_in[3];
    const float* Wkv_down  = (const float*)d_in[4];
    const float* kv_norm_w = (const float*)d_in[5];
    const float* Wkv_up    = (const float*)d_in[6];
    const float* Wo        = (const float*)d_in[7];
    float* out = (float*)d_out;

    float* ws     = (float*)d_ws;
    float* q_down = ws;                               // 2048*1536 f32 (reused as qbf later)
    float* qbuf   = q_down + (size_t)SLEN * QLR;      // 2048*3072 f32
    float* ckv    = qbuf + (size_t)SLEN * H * 192;    // 2048*576 f32
    float* attout = ckv + (size_t)SLEN * 576;         // 2048*2048 f32
    u16*   kvbf   = (u16*)(attout + (size_t)SLEN * HID); // 2048*4096 bf16
    u16*   krot   = kvbf + (size_t)SLEN * H * 256;    // 2048*64 bf16
    u16*   qbf    = (u16*)q_down;                     // overlay: 2048*3072 bf16 == q_down bytes

    dim3 blk(256);
    // 1) q_down = x @ Wq_down
    gemm_f32<<<dim3(QLR / 64, SLEN / 64), blk, 0, stream>>>(x, Wq_down, q_down, SLEN, QLR, HID, HID);
    // 2) rmsnorm(q_down)
    rmsnorm_rows<<<SLEN, blk, 0, stream>>>(q_down, q_norm_w, QLR, QLR);
    // 3) qbuf = q_down @ Wq_up
    gemm_f32<<<dim3((H * 192) / 64, SLEN / 64), blk, 0, stream>>>(q_down, Wq_up, qbuf, SLEN, H * 192, QLR, QLR);
    // 4) ckv = x @ Wkv_down
    gemm_f32<<<dim3(576 / 64, SLEN / 64), blk, 0, stream>>>(x, Wkv_down, ckv, SLEN, 576, HID, HID);
    // 5) rmsnorm(c)
    rmsnorm_rows<<<SLEN, blk, 0, stream>>>(ckv, kv_norm_w, 576, KVLR);
    // 6) kvbf = bf16(c @ Wkv_up)
    gemm_f32_bf16out<<<dim3((H * 256) / 64, SLEN / 64), blk, 0, stream>>>(ckv, Wkv_up, kvbf, SLEN, H * 256, KVLR, 576);
    // 7) RoPE + casts (reads qbuf fp32, writes qbf bf16 over old q_down)
    rope_cast<<<SLEN, blk, 0, stream>>>(qbuf, ckv, qbf, krot);
    // 8) MFMA flash attention
    attn_mfma<<<dim3(SLEN / 64, H), blk, 0, stream>>>(qbf, kvbf, krot, attout);
    // 9) out = attout @ Wo
    gemm_f32<<<dim3(HID / 64, SLEN / 64), blk, 0, stream>>>(attout, Wo, out, SLEN, HID, HID, HID);
}

// Round 3
// 331.928 us; speedup vs baseline: 10.3816x; 4.1721x over previous
//
#include <hip/hip_runtime.h>
#include <hip/hip_bf16.h>
#include <cstddef>

#define H 16
#define DN 128
#define DR 64
#define DV 128
#define QLR 1536
#define KVLR 512
#define HID 2048
#define SLEN 2048
#define EPS 1e-6f
#define SCALE 0.08838834764831845f   /* 1/sqrt(128) */

typedef __attribute__((ext_vector_type(8))) short short8;
typedef __attribute__((ext_vector_type(4))) float f32x4;
typedef unsigned short u16;

__device__ __forceinline__ u16 f2bf(float f) {
    __hip_bfloat16 h = __float2bfloat16(f);
    return __builtin_bit_cast(u16, h);
}
__device__ __forceinline__ float b2f(u16 v) {
    return __bfloat162float(__builtin_bit_cast(__hip_bfloat16, v));
}
__device__ __forceinline__ unsigned pack2(float a, float b) {
    return (unsigned)f2bf(a) | ((unsigned)f2bf(b) << 16);
}

// ---------------- elementwise f32 -> bf16 cast (one short8 per thread) ----------------
__global__ __launch_bounds__(256) void cast_f32_bf16(
    const float* __restrict__ in, u16* __restrict__ out)
{
    size_t base = ((size_t)blockIdx.x * 256 + threadIdx.x) * 8;
    float4 v0 = *reinterpret_cast<const float4*>(in + base);
    float4 v1 = *reinterpret_cast<const float4*>(in + base + 4);
    union { short8 s; unsigned u[4]; } p;
    p.u[0] = pack2(v0.x, v0.y); p.u[1] = pack2(v0.z, v0.w);
    p.u[2] = pack2(v1.x, v1.y); p.u[3] = pack2(v1.z, v1.w);
    *reinterpret_cast<short8*>(out + base) = p.s;
}

// ---------------- transpose-cast: W f32 [K][N] -> Wt bf16 [Npad][K] ----------------
// grid (Npad/64, K/64); N must be a multiple of 64; rows n>=N get zeros.
__global__ __launch_bounds__(256) void tcast_kernel(
    const float* __restrict__ W, u16* __restrict__ Wt, int K, int N)
{
    __shared__ float T[64][65];
    const int tid = threadIdx.x;
    const int n0 = blockIdx.x * 64, k0 = blockIdx.y * 64;
    const bool inb = (n0 < N);
    {
        int r = tid >> 4, c4 = (tid & 15) * 4;
        #pragma unroll
        for (int rr = 0; rr < 4; ++rr) {
            int row = rr * 16 + r;
            float4 v = inb ? *reinterpret_cast<const float4*>(W + (size_t)(k0 + row) * N + n0 + c4)
                           : make_float4(0.f, 0.f, 0.f, 0.f);
            T[row][c4] = v.x; T[row][c4 + 1] = v.y; T[row][c4 + 2] = v.z; T[row][c4 + 3] = v.w;
        }
    }
    __syncthreads();
    {
        int n = tid >> 2, kq = (tid & 3) * 16;
        unsigned u[8];
        #pragma unroll
        for (int jj = 0; jj < 8; ++jj)
            u[jj] = pack2(T[kq + 2 * jj][n], T[kq + 2 * jj + 1][n]);
        u16* dst = Wt + (size_t)(n0 + n) * K + k0 + kq;
        *reinterpret_cast<uint4*>(dst)     = make_uint4(u[0], u[1], u[2], u[3]);
        *reinterpret_cast<uint4*>(dst + 8) = make_uint4(u[4], u[5], u[6], u[7]);
    }
}

// ---------------- bf16 MFMA GEMM: C[M,N] = A[M,K] @ Bt[Npad,K]^T ----------------
// BM=BN=128, BK=32, 256 threads (2x2 waves of 64x64). LDS XOR-swizzled, double-buffered,
// staged via global_load_lds width=16 with pre-swizzled global source addresses.
__device__ __forceinline__ void stage4(const char* Gb, const unsigned* srcOff,
                                       const int* ldsBase, u16* smemBuf, unsigned koff)
{
    #pragma unroll
    for (int j = 0; j < 4; ++j)
        __builtin_amdgcn_global_load_lds(
            (const __attribute__((address_space(1))) unsigned int*)(Gb + srcOff[j] + koff),
            (__attribute__((address_space(3))) unsigned int*)(smemBuf + ldsBase[j]),
            16, 0, 0);
}

template<bool BF16OUT>
__global__ __launch_bounds__(256) void gemm_bf16(
    const u16* __restrict__ A, const u16* __restrict__ Bt,
    void* __restrict__ Cv, int M, int N, int K)
{
    __shared__ u16 smem[2][8192];   // [buf][ A tile 0..4095 | B tile 4096..8191 ] u16
    const int tid = threadIdx.x, lane = tid & 63, w = tid >> 6;
    const int m0 = blockIdx.y * 128, n0 = blockIdx.x * 128;
    const size_t Kb = (size_t)K * 2;

    // staging: wave w owns chunks 4w..4w+3 (chunks 0-7 = A tile, 8-15 = B tile)
    unsigned srcOff[4];
    int ldsBase[4];
    #pragma unroll
    for (int j = 0; j < 4; ++j) {
        int c = w * 4 + j;
        int o = (c & 7) * 1024 + lane * 16;             // byte offset in 8KB tile
        int u = o ^ (((o >> 7) & 3) << 4);              // un-swizzled logical offset
        int row = u >> 6, kbyte = u & 63;
        srcOff[j] = (unsigned)((size_t)((c < 8 ? m0 : n0) + row) * Kb + kbyte);
        ldsBase[j] = (c < 8) ? (c * 512) : (4096 + (c - 8) * 512);
    }
    const char* Gb = (w < 2) ? (const char*)A : (const char*)Bt;

    // fragment LDS byte offsets (swizzled)
    const int wr = (w >> 1) * 64, wc = (w & 1) * 64;
    int aoff[4], boff[4];
    #pragma unroll
    for (int i = 0; i < 4; ++i) {
        int oa = (wr + i * 16 + (lane & 15)) * 64 + (lane >> 4) * 16;
        aoff[i] = oa ^ (((oa >> 7) & 3) << 4);
        int ob = (wc + i * 16 + (lane & 15)) * 64 + (lane >> 4) * 16;
        boff[i] = (ob ^ (((ob >> 7) & 3) << 4)) + 8192;
    }

    f32x4 acc[4][4];
    #pragma unroll
    for (int i = 0; i < 4; ++i)
        #pragma unroll
        for (int j = 0; j < 4; ++j) acc[i][j] = (f32x4){0.f, 0.f, 0.f, 0.f};

    const int NT = K >> 5;
    stage4(Gb, srcOff, ldsBase, &smem[0][0], 0);
    __syncthreads();
    int cur = 0;
    for (int t = 0; t < NT; ++t) {
        if (t + 1 < NT) stage4(Gb, srcOff, ldsBase, &smem[cur ^ 1][0], (unsigned)(t + 1) * 64);
        const char* base = (const char*)&smem[cur][0];
        short8 af[4], bfr[4];
        #pragma unroll
        for (int i = 0; i < 4; ++i) af[i] = *reinterpret_cast<const short8*>(base + aoff[i]);
        #pragma unroll
        for (int i = 0; i < 4; ++i) bfr[i] = *reinterpret_cast<const short8*>(base + boff[i]);
        __builtin_amdgcn_s_setprio(1);
        #pragma unroll
        for (int i = 0; i < 4; ++i)
            #pragma unroll
            for (int j = 0; j < 4; ++j)
                acc[i][j] = __builtin_amdgcn_mfma_f32_16x16x32_bf16(af[i], bfr[j], acc[i][j], 0, 0, 0);
        __builtin_amdgcn_s_setprio(0);
        __syncthreads();
        cur ^= 1;
    }

    // epilogue: C layout col=lane&15, row=(lane>>4)*4+reg
    #pragma unroll
    for (int i = 0; i < 4; ++i) {
        int grow0 = m0 + wr + i * 16 + ((lane >> 4) * 4);
        #pragma unroll
        for (int j = 0; j < 4; ++j) {
            int gcol = n0 + wc + j * 16 + (lane & 15);
            if (gcol < N) {
                #pragma unroll
                for (int r = 0; r < 4; ++r) {
                    float v = acc[i][j][r];
                    if (BF16OUT) ((u16*)Cv)[(size_t)(grow0 + r) * N + gcol] = f2bf(v);
                    else         ((float*)Cv)[(size_t)(grow0 + r) * N + gcol] = v;
                }
            }
        }
    }
}

// ---------------- RMSNorm: fp32 in (strided) -> bf16 out ----------------
__global__ __launch_bounds__(256) void rmsnorm_bf16(
    const float* __restrict__ in, const float* __restrict__ wgt,
    u16* __restrict__ out, int inStride, int outStride, int D)
{
    const int row = blockIdx.x, tid = threadIdx.x;
    const float* p = in + (size_t)row * inStride;
    float ss = 0.f;
    for (int i = tid * 4; i < D; i += 1024) {
        float4 v = *reinterpret_cast<const float4*>(p + i);
        ss += v.x * v.x + v.y * v.y + v.z * v.z + v.w * v.w;
    }
    __shared__ float wsum[4];
    int lane = tid & 63, wv = tid >> 6;
    #pragma unroll
    for (int off = 32; off; off >>= 1) ss += __shfl_down(ss, off);
    if (lane == 0) wsum[wv] = ss;
    __syncthreads();
    if (tid == 0) {
        float t = wsum[0] + wsum[1] + wsum[2] + wsum[3];
        wsum[0] = rsqrtf(t / (float)D + EPS);
    }
    __syncthreads();
    float sc = wsum[0];
    for (int i = tid * 4; i < D; i += 1024) {
        float4 v = *reinterpret_cast<const float4*>(p + i);
        float4 g = *reinterpret_cast<const float4*>(wgt + i);
        unsigned lo = pack2(v.x * sc * g.x, v.y * sc * g.y);
        unsigned hi = pack2(v.z * sc * g.z, v.w * sc * g.w);
        *reinterpret_cast<uint2*>(out + (size_t)row * outStride + i) = make_uint2(lo, hi);
    }
}

// ---------------- RoPE in place on bf16 q + krot from fp32 ckv ----------------
__global__ __launch_bounds__(256) void rope_bf16(
    u16* __restrict__ q, const float* __restrict__ ckv, u16* __restrict__ krot)
{
    const int s = blockIdx.x, tid = threadIdx.x;
    __shared__ float cs[32], sn[32];
    if (tid < 32) {
        float inv = powf(10000.0f, -(float)tid / 32.0f);
        float ang = (float)s * inv;
        cs[tid] = cosf(ang); sn[tid] = sinf(ang);
    }
    __syncthreads();
    float ev[2], ov[2]; int hh[2], ii[2];
    #pragma unroll
    for (int it = 0; it < 2; ++it) {
        int pidx = tid + it * 256;         // 0..511 = H*32 pairs
        int h = pidx >> 5, i = pidx & 31;
        hh[it] = h; ii[it] = i;
        const u16* base = q + (size_t)s * 3072 + h * 192 + 128;
        ev[it] = b2f(base[2 * i]); ov[it] = b2f(base[2 * i + 1]);
    }
    __syncthreads();
    #pragma unroll
    for (int it = 0; it < 2; ++it) {
        int h = hh[it], i = ii[it];
        u16* base = q + (size_t)s * 3072 + h * 192 + 128;
        base[i]      = f2bf(ev[it] * cs[i] - ov[it] * sn[i]);
        base[32 + i] = f2bf(ov[it] * cs[i] + ev[it] * sn[i]);
    }
    if (tid < 32) {
        int i = tid;
        float e = ckv[(size_t)s * 576 + 512 + 2 * i];
        float o = ckv[(size_t)s * 576 + 512 + 2 * i + 1];
        krot[(size_t)s * 64 + i]      = f2bf(e * cs[i] - o * sn[i]);
        krot[(size_t)s * 64 + 32 + i] = f2bf(o * cs[i] + e * sn[i]);
    }
}

// ---------------- MFMA flash attention ----------------
// grid (32 qblocks of 64 rows, 16 heads); 256 threads = 4 waves; KB=32 keys/iter.
// Q in registers; V in XOR-swizzled transposed LDS; qb order reversed.
__global__ __launch_bounds__(256) void attn_mfma(
    const u16* __restrict__ qbf,   // [S][H][192]  (rope applied, bf16)
    const u16* __restrict__ kvbf,  // [S][H][256]  (k_nope | v)
    const u16* __restrict__ krot,  // [S][64]
    u16* __restrict__ outb)        // [S][2048] bf16
{
    const int h = blockIdx.y;
    const int qb = (int)(gridDim.x - 1 - blockIdx.x);
    const int s0 = qb * 64;
    const int tid = threadIdx.x, lane = tid & 63, w = tid >> 6;

    __shared__ u16 Ks[32][200];
    __shared__ u16 Vt[128 * 40];   // logical Vt[c][t] at c*40 + (t ^ (((c>>3)&3)<<3))
    __shared__ u16 Ps[64][40];

    const int colk = lane & 15;
    const int g8 = (lane >> 4) * 8;

    // Q fragments in registers (wave w rows w*16..w*16+15)
    short8 qreg[6];
    {
        const u16* qp = qbf + ((size_t)(s0 + w * 16 + colk) * H + h) * 192;
        #pragma unroll
        for (int ks = 0; ks < 6; ++ks)
            qreg[ks] = *reinterpret_cast<const short8*>(qp + ks * 32 + g8);
    }

    float m_run[4] = {-1e30f, -1e30f, -1e30f, -1e30f};
    float l_run[4] = {0.f, 0.f, 0.f, 0.f};
    f32x4 acc_o[8];
    #pragma unroll
    for (int i = 0; i < 8; ++i) acc_o[i] = (f32x4){0.f, 0.f, 0.f, 0.f};

    const int nkt = 2 * qb + 2;
    for (int kb = 0; kb < nkt; ++kb) {
        __syncthreads();   // previous iteration done reading Ks/Vt
        // stage K tile: 32 keys x 192 (k_nope | k_rot), short8 chunks
        #pragma unroll
        for (int it = 0; it < 3; ++it) {
            int c = it * 256 + tid;
            int t = c / 24, d0 = (c % 24) * 8;
            int gk = kb * 32 + t;
            const u16* src = (d0 < 128)
                ? kvbf + ((size_t)gk * H + h) * 256 + d0
                : krot + (size_t)gk * 64 + (d0 - 128);
            *reinterpret_cast<short8*>(&Ks[t][d0]) = *reinterpret_cast<const short8*>(src);
        }
        // stage V transposed+swizzled: short8 global loads, scalar swizzled LDS writes
        #pragma unroll
        for (int it = 0; it < 2; ++it) {
            int chunk = it * 256 + tid;
            int t = chunk >> 4, c0 = (chunk & 15) * 8;
            short8 v = *reinterpret_cast<const short8*>(
                kvbf + ((size_t)(kb * 32 + t) * H + h) * 256 + 128 + c0);
            #pragma unroll
            for (int j = 0; j < 8; ++j) {
                int c = c0 + j;
                Vt[c * 40 + (t ^ (((c >> 3) & 3) << 3))] = (u16)v[j];
            }
        }
        __syncthreads();

        // QK^T
        f32x4 sacc0 = (f32x4){0.f, 0.f, 0.f, 0.f};
        f32x4 sacc1 = (f32x4){0.f, 0.f, 0.f, 0.f};
        __builtin_amdgcn_s_setprio(1);
        #pragma unroll
        for (int ks = 0; ks < 6; ++ks) {
            short8 b0 = *reinterpret_cast<const short8*>(&Ks[colk][ks * 32 + g8]);
            short8 b1 = *reinterpret_cast<const short8*>(&Ks[16 + colk][ks * 32 + g8]);
            sacc0 = __builtin_amdgcn_mfma_f32_16x16x32_bf16(qreg[ks], b0, sacc0, 0, 0, 0);
            sacc1 = __builtin_amdgcn_mfma_f32_16x16x32_bf16(qreg[ks], b1, sacc1, 0, 0, 0);
        }
        __builtin_amdgcn_s_setprio(0);

        // in-register online softmax (row = w*16 + (lane>>4)*4 + reg, keys across 16 lanes)
        const int key0 = kb * 32 + colk, key1 = key0 + 16;
        const int rbase = s0 + w * 16 + (lane >> 4) * 4;
        #pragma unroll
        for (int reg = 0; reg < 4; ++reg) {
            int qg = rbase + reg;
            float sv0 = (key0 <= qg) ? sacc0[reg] * SCALE : -1e30f;
            float sv1 = (key1 <= qg) ? sacc1[reg] * SCALE : -1e30f;
            float mx = fmaxf(sv0, sv1);
            mx = fmaxf(mx, __shfl_xor(mx, 1));
            mx = fmaxf(mx, __shfl_xor(mx, 2));
            mx = fmaxf(mx, __shfl_xor(mx, 4));
            mx = fmaxf(mx, __shfl_xor(mx, 8));
            float mnew = fmaxf(m_run[reg], mx);
            float f = __expf(m_run[reg] - mnew);
            m_run[reg] = mnew;
            float p0 = __expf(sv0 - mnew);
            float p1 = __expf(sv1 - mnew);
            float rs = p0 + p1;
            rs += __shfl_xor(rs, 1);
            rs += __shfl_xor(rs, 2);
            rs += __shfl_xor(rs, 4);
            rs += __shfl_xor(rs, 8);
            l_run[reg] = l_run[reg] * f + rs;
            #pragma unroll
            for (int ct = 0; ct < 8; ++ct) acc_o[ct][reg] *= f;
            int prow = w * 16 + (lane >> 4) * 4 + reg;
            Ps[prow][colk]      = f2bf(p0);
            Ps[prow][16 + colk] = f2bf(p1);
        }
        __syncthreads();   // Ps visible before b128 reads

        // PV: O[16x128] += P[16x32] @ V[32x128]
        short8 pa = *reinterpret_cast<const short8*>(&Ps[w * 16 + colk][g8]);
        __builtin_amdgcn_s_setprio(1);
        #pragma unroll
        for (int ct = 0; ct < 8; ++ct) {
            int c = ct * 16 + colk;
            short8 vb = *reinterpret_cast<const short8*>(&Vt[c * 40 + (g8 ^ (((c >> 3) & 3) << 3))]);
            acc_o[ct] = __builtin_amdgcn_mfma_f32_16x16x32_bf16(pa, vb, acc_o[ct], 0, 0, 0);
        }
        __builtin_amdgcn_s_setprio(0);
    }

    // epilogue: normalize, store bf16
    #pragma unroll
    for (int reg = 0; reg < 4; ++reg) {
        float invl = 1.0f / l_run[reg];
        int row = s0 + w * 16 + (lane >> 4) * 4 + reg;
        #pragma unroll
        for (int ct = 0; ct < 8; ++ct)
            outb[(size_t)row * 2048 + h * 128 + ct * 16 + colk] = f2bf(acc_o[ct][reg] * invl);
    }
}

extern "C" void kernel_launch(void* const* d_in, const int* in_sizes, int n_in,
                              void* d_out, int out_size, void* d_ws, size_t ws_size,
                              hipStream_t stream)
{
    (void)in_sizes; (void)n_in; (void)out_size; (void)ws_size;
    const float* x         = (const float*)d_in[0];
    const float* Wq_down   = (const float*)d_in[1];
    const float* q_norm_w  = (const float*)d_in[2];
    const float* Wq_up     = (const float*)d_in[3];
    const float* Wkv_down  = (const float*)d_in[4];
    const float* kv_norm_w = (const float*)d_in[5];
    const float* Wkv_up    = (const float*)d_in[6];
    const float* Wo        = (const float*)d_in[7];
    float* out = (float*)d_out;

    char* p = (char*)d_ws;
    u16* xb      = (u16*)p;                 p += (size_t)2048 * 2048 * 2;   // 8 MB
    char* aliasb = p;
    u16* Wqd_t   = (u16*)p;                 p += (size_t)1536 * 2048 * 2;   // 6 MB
    u16* Wqu_t   = (u16*)p;                 p += (size_t)3072 * 1536 * 2;   // 9 MB
    u16* Wkvd_t  = (u16*)p;                 p += (size_t)640  * 2048 * 2;   // 2.5 MB
    u16* Wkvu_t  = (u16*)p;                 p += (size_t)4096 * 512  * 2;   // 4 MB
    u16* Wo_t    = (u16*)p;                 p += (size_t)2048 * 2048 * 2;   // 8 MB
    float* qd    = (float*)p;               p += (size_t)2048 * 1536 * 4;   // 12 MB
    u16* qdb     = (u16*)p;                 p += (size_t)2048 * 1536 * 2;   // 6 MB
    u16* qbuf    = (u16*)p;                 p += (size_t)2048 * 3072 * 2;   // 12 MB
    float* ckv   = (float*)p;               p += (size_t)2048 * 576  * 4;   // 4.5 MB
    u16* ckvb    = (u16*)p;                 p += (size_t)2048 * 512  * 2;   // 2 MB
    u16* kvbf    = (u16*)p;                 p += (size_t)2048 * 4096 * 2;   // 16 MB
    u16* krotb   = (u16*)p;                 p += (size_t)2048 * 64   * 2;   // 0.25 MB
    u16* attb    = (u16*)aliasb;            // aliases Wqd_t/Wqu_t (dead before attn)

    dim3 blk(256);
    // casts / transposes
    cast_f32_bf16<<<2048, blk, 0, stream>>>(x, xb);
    tcast_kernel<<<dim3(24, 32), blk, 0, stream>>>(Wq_down, Wqd_t, 2048, 1536);
    tcast_kernel<<<dim3(48, 24), blk, 0, stream>>>(Wq_up,   Wqu_t, 1536, 3072);
    tcast_kernel<<<dim3(10, 32), blk, 0, stream>>>(Wkv_down, Wkvd_t, 2048, 576);
    tcast_kernel<<<dim3(64, 8),  blk, 0, stream>>>(Wkv_up,  Wkvu_t, 512, 4096);
    tcast_kernel<<<dim3(32, 32), blk, 0, stream>>>(Wo,      Wo_t,  2048, 2048);
    // pipeline
    gemm_bf16<false><<<dim3(12, 16), blk, 0, stream>>>(xb, Wqd_t, qd, 2048, 1536, 2048);
    rmsnorm_bf16<<<2048, blk, 0, stream>>>(qd, q_norm_w, qdb, 1536, 1536, 1536);
    gemm_bf16<true><<<dim3(24, 16), blk, 0, stream>>>(qdb, Wqu_t, qbuf, 2048, 3072, 1536);
    gemm_bf16<false><<<dim3(5, 16), blk, 0, stream>>>(xb, Wkvd_t, ckv, 2048, 576, 2048);
    rmsnorm_bf16<<<2048, blk, 0, stream>>>(ckv, kv_norm_w, ckvb, 576, 512, 512);
    gemm_bf16<true><<<dim3(32, 16), blk, 0, stream>>>(ckvb, Wkvu_t, kvbf, 2048, 4096, 512);
    rope_bf16<<<2048, blk, 0, stream>>>(qbuf, ckv, krotb);
    attn_mfma<<<dim3(32, 16), blk, 0, stream>>>(qbuf, kvbf, krotb, attb);
    gemm_bf16<false><<<dim3(16, 16), blk, 0, stream>>>(attb, Wo_t, out, 2048, 2048, 2048);
}

// Round 4
// 304.176 us; speedup vs baseline: 11.3288x; 1.0912x over previous
//
#include <hip/hip_runtime.h>
#include <hip/hip_bf16.h>
#include <cstddef>

#define H 16
#define DN 128
#define DR 64
#define DV 128
#define QLR 1536
#define KVLR 512
#define HID 2048
#define SLEN 2048
#define EPS 1e-6f
#define SCALE 0.08838834764831845f   /* 1/sqrt(128) */

typedef __attribute__((ext_vector_type(8))) short short8;
typedef __attribute__((ext_vector_type(4))) float f32x4;
typedef unsigned short u16;

__device__ __forceinline__ u16 f2bf(float f) {
    __hip_bfloat16 h = __float2bfloat16(f);
    return __builtin_bit_cast(u16, h);
}
__device__ __forceinline__ float b2f(u16 v) {
    return __bfloat162float(__builtin_bit_cast(__hip_bfloat16, v));
}
__device__ __forceinline__ unsigned pack2(float a, float b) {
    return (unsigned)f2bf(a) | ((unsigned)f2bf(b) << 16);
}

// ---------------- elementwise f32 -> bf16 cast ----------------
__global__ __launch_bounds__(256) void cast_f32_bf16(
    const float* __restrict__ in, u16* __restrict__ out)
{
    size_t base = ((size_t)blockIdx.x * 256 + threadIdx.x) * 8;
    float4 v0 = *reinterpret_cast<const float4*>(in + base);
    float4 v1 = *reinterpret_cast<const float4*>(in + base + 4);
    union { short8 s; unsigned u[4]; } p;
    p.u[0] = pack2(v0.x, v0.y); p.u[1] = pack2(v0.z, v0.w);
    p.u[2] = pack2(v1.x, v1.y); p.u[3] = pack2(v1.z, v1.w);
    *reinterpret_cast<short8*>(out + base) = p.s;
}

// ---------------- transpose-cast: W f32 [K][N] -> Wt bf16 [Npad][K], optional scale ----------------
__global__ __launch_bounds__(256) void tcast_kernel(
    const float* __restrict__ W, u16* __restrict__ Wt, int K, int N, float scale)
{
    __shared__ float T[64][65];
    const int tid = threadIdx.x;
    const int n0 = blockIdx.x * 64, k0 = blockIdx.y * 64;
    const bool inb = (n0 < N);
    {
        int r = tid >> 4, c4 = (tid & 15) * 4;
        #pragma unroll
        for (int rr = 0; rr < 4; ++rr) {
            int row = rr * 16 + r;
            float4 v = inb ? *reinterpret_cast<const float4*>(W + (size_t)(k0 + row) * N + n0 + c4)
                           : make_float4(0.f, 0.f, 0.f, 0.f);
            T[row][c4] = v.x * scale; T[row][c4 + 1] = v.y * scale;
            T[row][c4 + 2] = v.z * scale; T[row][c4 + 3] = v.w * scale;
        }
    }
    __syncthreads();
    {
        int n = tid >> 2, kq = (tid & 3) * 16;
        unsigned u[8];
        #pragma unroll
        for (int jj = 0; jj < 8; ++jj)
            u[jj] = pack2(T[kq + 2 * jj][n], T[kq + 2 * jj + 1][n]);
        u16* dst = Wt + (size_t)(n0 + n) * K + k0 + kq;
        *reinterpret_cast<uint4*>(dst)     = make_uint4(u[0], u[1], u[2], u[3]);
        *reinterpret_cast<uint4*>(dst + 8) = make_uint4(u[4], u[5], u[6], u[7]);
    }
}

// ---------------- bf16 MFMA GEMM: C[M,N] = A[M,K] @ Bt[Npad,K]^T ----------------
__device__ __forceinline__ void stage4(const char* Gb, const unsigned* srcOff,
                                       const int* ldsBase, u16* smemBuf, unsigned koff)
{
    #pragma unroll
    for (int j = 0; j < 4; ++j)
        __builtin_amdgcn_global_load_lds(
            (const __attribute__((address_space(1))) unsigned int*)(Gb + srcOff[j] + koff),
            (__attribute__((address_space(3))) unsigned int*)(smemBuf + ldsBase[j]),
            16, 0, 0);
}

template<bool BF16OUT>
__global__ __launch_bounds__(256) void gemm_bf16(
    const u16* __restrict__ A, const u16* __restrict__ Bt,
    void* __restrict__ Cv, int M, int N, int K)
{
    __shared__ u16 smem[2][8192];
    const int tid = threadIdx.x, lane = tid & 63, w = tid >> 6;
    const int m0 = blockIdx.y * 128, n0 = blockIdx.x * 128;
    const size_t Kb = (size_t)K * 2;

    unsigned srcOff[4];
    int ldsBase[4];
    #pragma unroll
    for (int j = 0; j < 4; ++j) {
        int c = w * 4 + j;
        int o = (c & 7) * 1024 + lane * 16;
        int u = o ^ (((o >> 7) & 3) << 4);
        int row = u >> 6, kbyte = u & 63;
        srcOff[j] = (unsigned)((size_t)((c < 8 ? m0 : n0) + row) * Kb + kbyte);
        ldsBase[j] = (c < 8) ? (c * 512) : (4096 + (c - 8) * 512);
    }
    const char* Gb = (w < 2) ? (const char*)A : (const char*)Bt;

    const int wr = (w >> 1) * 64, wc = (w & 1) * 64;
    int aoff[4], boff[4];
    #pragma unroll
    for (int i = 0; i < 4; ++i) {
        int oa = (wr + i * 16 + (lane & 15)) * 64 + (lane >> 4) * 16;
        aoff[i] = oa ^ (((oa >> 7) & 3) << 4);
        int ob = (wc + i * 16 + (lane & 15)) * 64 + (lane >> 4) * 16;
        boff[i] = (ob ^ (((ob >> 7) & 3) << 4)) + 8192;
    }

    f32x4 acc[4][4];
    #pragma unroll
    for (int i = 0; i < 4; ++i)
        #pragma unroll
        for (int j = 0; j < 4; ++j) acc[i][j] = (f32x4){0.f, 0.f, 0.f, 0.f};

    const int NT = K >> 5;
    stage4(Gb, srcOff, ldsBase, &smem[0][0], 0);
    __syncthreads();
    int cur = 0;
    for (int t = 0; t < NT; ++t) {
        if (t + 1 < NT) stage4(Gb, srcOff, ldsBase, &smem[cur ^ 1][0], (unsigned)(t + 1) * 64);
        const char* base = (const char*)&smem[cur][0];
        short8 af[4], bfr[4];
        #pragma unroll
        for (int i = 0; i < 4; ++i) af[i] = *reinterpret_cast<const short8*>(base + aoff[i]);
        #pragma unroll
        for (int i = 0; i < 4; ++i) bfr[i] = *reinterpret_cast<const short8*>(base + boff[i]);
        __builtin_amdgcn_s_setprio(1);
        #pragma unroll
        for (int i = 0; i < 4; ++i)
            #pragma unroll
            for (int j = 0; j < 4; ++j)
                acc[i][j] = __builtin_amdgcn_mfma_f32_16x16x32_bf16(af[i], bfr[j], acc[i][j], 0, 0, 0);
        __builtin_amdgcn_s_setprio(0);
        __syncthreads();
        cur ^= 1;
    }

    #pragma unroll
    for (int i = 0; i < 4; ++i) {
        int grow0 = m0 + wr + i * 16 + ((lane >> 4) * 4);
        #pragma unroll
        for (int j = 0; j < 4; ++j) {
            int gcol = n0 + wc + j * 16 + (lane & 15);
            if (gcol < N) {
                #pragma unroll
                for (int r = 0; r < 4; ++r) {
                    float v = acc[i][j][r];
                    if (BF16OUT) ((u16*)Cv)[(size_t)(grow0 + r) * N + gcol] = f2bf(v);
                    else         ((float*)Cv)[(size_t)(grow0 + r) * N + gcol] = v;
                }
            }
        }
    }
}

// ---------------- RMSNorm: fp32 in (strided) -> bf16 out ----------------
__global__ __launch_bounds__(256) void rmsnorm_bf16(
    const float* __restrict__ in, const float* __restrict__ wgt,
    u16* __restrict__ out, int inStride, int outStride, int D)
{
    const int row = blockIdx.x, tid = threadIdx.x;
    const float* p = in + (size_t)row * inStride;
    float ss = 0.f;
    for (int i = tid * 4; i < D; i += 1024) {
        float4 v = *reinterpret_cast<const float4*>(p + i);
        ss += v.x * v.x + v.y * v.y + v.z * v.z + v.w * v.w;
    }
    __shared__ float wsum[4];
    int lane = tid & 63, wv = tid >> 6;
    #pragma unroll
    for (int off = 32; off; off >>= 1) ss += __shfl_down(ss, off);
    if (lane == 0) wsum[wv] = ss;
    __syncthreads();
    if (tid == 0) {
        float t = wsum[0] + wsum[1] + wsum[2] + wsum[3];
        wsum[0] = rsqrtf(t / (float)D + EPS);
    }
    __syncthreads();
    float sc = wsum[0];
    for (int i = tid * 4; i < D; i += 1024) {
        float4 v = *reinterpret_cast<const float4*>(p + i);
        float4 g = *reinterpret_cast<const float4*>(wgt + i);
        unsigned lo = pack2(v.x * sc * g.x, v.y * sc * g.y);
        unsigned hi = pack2(v.z * sc * g.z, v.w * sc * g.w);
        *reinterpret_cast<uint2*>(out + (size_t)row * outStride + i) = make_uint2(lo, hi);
    }
}

// ---------------- RoPE in place on bf16 q + krot from fp32 ckv ----------------
__global__ __launch_bounds__(256) void rope_bf16(
    u16* __restrict__ q, const float* __restrict__ ckv, u16* __restrict__ krot)
{
    const int s = blockIdx.x, tid = threadIdx.x;
    __shared__ float cs[32], sn[32];
    if (tid < 32) {
        float inv = powf(10000.0f, -(float)tid / 32.0f);
        float ang = (float)s * inv;
        cs[tid] = cosf(ang); sn[tid] = sinf(ang);
    }
    __syncthreads();
    float ev[2], ov[2]; int hh[2], ii[2];
    #pragma unroll
    for (int it = 0; it < 2; ++it) {
        int pidx = tid + it * 256;
        int h = pidx >> 5, i = pidx & 31;
        hh[it] = h; ii[it] = i;
        const u16* base = q + (size_t)s * 3072 + h * 192 + 128;
        ev[it] = b2f(base[2 * i]); ov[it] = b2f(base[2 * i + 1]);
    }
    __syncthreads();
    #pragma unroll
    for (int it = 0; it < 2; ++it) {
        int h = hh[it], i = ii[it];
        u16* base = q + (size_t)s * 3072 + h * 192 + 128;
        base[i]      = f2bf(ev[it] * cs[i] - ov[it] * sn[i]);
        base[32 + i] = f2bf(ov[it] * cs[i] + ev[it] * sn[i]);
    }
    if (tid < 32) {
        int i = tid;
        float e = ckv[(size_t)s * 576 + 512 + 2 * i];
        float o = ckv[(size_t)s * 576 + 512 + 2 * i + 1];
        krot[(size_t)s * 64 + i]      = f2bf(e * cs[i] - o * sn[i]);
        krot[(size_t)s * 64 + 32 + i] = f2bf(o * cs[i] + e * sn[i]);
    }
}

// ---------------- MFMA flash attention, pipelined ----------------
// 512 blocks (XCD-mapped), 256 threads = 4 waves; KB=32 keys/iter, double-buffered.
__device__ __forceinline__ int vt_swz(int a) {
    return a ^ (((((a >> 7) & 7) ^ ((a >> 10) & 7))) << 4);
}

__global__ __launch_bounds__(256, 2) void attn_mfma(
    const u16* __restrict__ qbf,   // [S][H][192]  (rope applied, pre-scaled)
    const u16* __restrict__ kvbf,  // [S][H][256]  (k_nope | v)
    const u16* __restrict__ krot,  // [S][64]
    u16* __restrict__ outb)        // [S][2048] bf16
{
    // XCD-aware mapping: all q-blocks of a head on one XCD; balanced qb order.
    const int bid = blockIdx.x;
    const int xcd = bid & 7, slot = bid >> 3;
    const int h = xcd + 8 * (slot >> 5);
    const int inner = slot & 31;
    const int qb = (inner & 1) ? (31 - (inner >> 1)) : (inner >> 1);
    const int s0 = qb * 64;
    const int tid = threadIdx.x, lane = tid & 63, w = tid >> 6;

    __shared__ u16 Ks[2][32 * 200];   // [buf][key*200 + d], 2-way banks on frag reads
    __shared__ u16 Vt[2][128 * 64];   // [buf] swizzled transposed V
    __shared__ u16 Ps[64][40];        // wave-private P rows

    const int colk = lane & 15;
    const int g8 = (lane >> 4) * 8;

    // Q fragments in registers (pre-scaled by SCALE via Wq_up)
    short8 qreg[6];
    {
        const u16* qp = qbf + ((size_t)(s0 + w * 16 + colk) * H + h) * 192;
        #pragma unroll
        for (int ks = 0; ks < 6; ++ks)
            qreg[ks] = *reinterpret_cast<const short8*>(qp + ks * 32 + g8);
    }

    // staging geometry (per thread): K 3 chunks, V 2 chunks
    int kt[3], kd0[3];
    #pragma unroll
    for (int it = 0; it < 3; ++it) {
        int c = it * 256 + tid;
        kt[it] = c / 24; kd0[it] = (c % 24) * 8;
    }
    int vt_[2], vc0[2];
    #pragma unroll
    for (int it = 0; it < 2; ++it) {
        int c = it * 256 + tid;
        vt_[it] = c >> 4; vc0[it] = (c & 15) * 8;
    }

    float m_run[4] = {-1e30f, -1e30f, -1e30f, -1e30f};
    float l_run[4] = {0.f, 0.f, 0.f, 0.f};
    f32x4 acc_o[8];
    #pragma unroll
    for (int i = 0; i < 8; ++i) acc_o[i] = (f32x4){0.f, 0.f, 0.f, 0.f};

    const int nkt = 2 * qb + 2;
    short8 kreg[3], vreg[2];

    // ---- load tile kb into registers ----
    auto issue_loads = [&](int kb) {
        #pragma unroll
        for (int it = 0; it < 3; ++it) {
            int gk = kb * 32 + kt[it];
            const u16* src = (kd0[it] < 128)
                ? kvbf + ((size_t)gk * H + h) * 256 + kd0[it]
                : krot + (size_t)gk * 64 + (kd0[it] - 128);
            kreg[it] = *reinterpret_cast<const short8*>(src);
        }
        #pragma unroll
        for (int it = 0; it < 2; ++it)
            vreg[it] = *reinterpret_cast<const short8*>(
                kvbf + ((size_t)(kb * 32 + vt_[it]) * H + h) * 256 + 128 + vc0[it]);
    };
    // ---- write registers to LDS buffer ----
    auto write_lds = [&](int buf) {
        #pragma unroll
        for (int it = 0; it < 3; ++it)
            *reinterpret_cast<short8*>(&Ks[buf][kt[it] * 200 + kd0[it]]) = kreg[it];
        #pragma unroll
        for (int it = 0; it < 2; ++it) {
            #pragma unroll
            for (int j = 0; j < 8; ++j) {
                int c = vc0[it] + j;
                int a = c * 128 + vt_[it] * 2;
                Vt[buf][vt_swz(a) >> 1] = (u16)vreg[it][j];
            }
        }
    };

    issue_loads(0);
    write_lds(0);
    __syncthreads();

    for (int kb = 0; kb < nkt; ++kb) {
        const int cur = kb & 1;
        const bool pf = (kb + 1 < nkt);
        if (pf) issue_loads(kb + 1);

        // QK^T on Ks[cur]
        f32x4 sacc0 = (f32x4){0.f, 0.f, 0.f, 0.f};
        f32x4 sacc1 = (f32x4){0.f, 0.f, 0.f, 0.f};
        __builtin_amdgcn_s_setprio(1);
        #pragma unroll
        for (int ks = 0; ks < 6; ++ks) {
            short8 b0 = *reinterpret_cast<const short8*>(&Ks[cur][colk * 200 + ks * 32 + g8]);
            short8 b1 = *reinterpret_cast<const short8*>(&Ks[cur][(16 + colk) * 200 + ks * 32 + g8]);
            sacc0 = __builtin_amdgcn_mfma_f32_16x16x32_bf16(qreg[ks], b0, sacc0, 0, 0, 0);
            sacc1 = __builtin_amdgcn_mfma_f32_16x16x32_bf16(qreg[ks], b1, sacc1, 0, 0, 0);
        }
        __builtin_amdgcn_s_setprio(0);

        // online softmax (rows wave-private); defer-max rescale skip
        const int key0 = kb * 32 + colk, key1 = key0 + 16;
        const int rbase = s0 + w * 16 + (lane >> 4) * 4;
        float sv0[4], sv1[4], mx[4];
        #pragma unroll
        for (int reg = 0; reg < 4; ++reg) {
            int qg = rbase + reg;
            sv0[reg] = (key0 <= qg) ? sacc0[reg] : -1e30f;
            sv1[reg] = (key1 <= qg) ? sacc1[reg] : -1e30f;
            float m = fmaxf(sv0[reg], sv1[reg]);
            m = fmaxf(m, __shfl_xor(m, 1));
            m = fmaxf(m, __shfl_xor(m, 2));
            m = fmaxf(m, __shfl_xor(m, 4));
            m = fmaxf(m, __shfl_xor(m, 8));
            mx[reg] = m;
        }
        bool small = (mx[0] <= m_run[0] + 8.f) && (mx[1] <= m_run[1] + 8.f) &&
                     (mx[2] <= m_run[2] + 8.f) && (mx[3] <= m_run[3] + 8.f);
        if (!__all(small)) {
            #pragma unroll
            for (int reg = 0; reg < 4; ++reg) {
                float mnew = fmaxf(m_run[reg], mx[reg]);
                float f = __expf(m_run[reg] - mnew);
                m_run[reg] = mnew;
                l_run[reg] *= f;
                #pragma unroll
                for (int ct = 0; ct < 8; ++ct) acc_o[ct][reg] *= f;
            }
        }
        #pragma unroll
        for (int reg = 0; reg < 4; ++reg) {
            float p0 = __expf(sv0[reg] - m_run[reg]);
            float p1 = __expf(sv1[reg] - m_run[reg]);
            float rs = p0 + p1;
            rs += __shfl_xor(rs, 1);
            rs += __shfl_xor(rs, 2);
            rs += __shfl_xor(rs, 4);
            rs += __shfl_xor(rs, 8);
            l_run[reg] += rs;
            int prow = w * 16 + (lane >> 4) * 4 + reg;
            Ps[prow][colk]      = f2bf(p0);
            Ps[prow][16 + colk] = f2bf(p1);
        }

        // stage next tile into other LDS buffer (auto-waits on global loads)
        if (pf) write_lds(cur ^ 1);

        // PV on Vt[cur] (Ps rows are wave-private; in-wave LDS ordering suffices)
        short8 pa = *reinterpret_cast<const short8*>(&Ps[w * 16 + colk][g8]);
        __builtin_amdgcn_s_setprio(1);
        #pragma unroll
        for (int ct = 0; ct < 8; ++ct) {
            int c = ct * 16 + colk;
            int a = c * 128 + g8 * 2;
            short8 vb = *reinterpret_cast<const short8*>(
                (const char*)&Vt[cur][0] + vt_swz(a));
            acc_o[ct] = __builtin_amdgcn_mfma_f32_16x16x32_bf16(pa, vb, acc_o[ct], 0, 0, 0);
        }
        __builtin_amdgcn_s_setprio(0);

        __syncthreads();
    }

    #pragma unroll
    for (int reg = 0; reg < 4; ++reg) {
        float invl = 1.0f / l_run[reg];
        int row = s0 + w * 16 + (lane >> 4) * 4 + reg;
        #pragma unroll
        for (int ct = 0; ct < 8; ++ct)
            outb[(size_t)row * 2048 + h * 128 + ct * 16 + colk] = f2bf(acc_o[ct][reg] * invl);
    }
}

extern "C" void kernel_launch(void* const* d_in, const int* in_sizes, int n_in,
                              void* d_out, int out_size, void* d_ws, size_t ws_size,
                              hipStream_t stream)
{
    (void)in_sizes; (void)n_in; (void)out_size; (void)ws_size;
    const float* x         = (const float*)d_in[0];
    const float* Wq_down   = (const float*)d_in[1];
    const float* q_norm_w  = (const float*)d_in[2];
    const float* Wq_up     = (const float*)d_in[3];
    const float* Wkv_down  = (const float*)d_in[4];
    const float* kv_norm_w = (const float*)d_in[5];
    const float* Wkv_up    = (const float*)d_in[6];
    const float* Wo        = (const float*)d_in[7];
    float* out = (float*)d_out;

    char* p = (char*)d_ws;
    u16* xb      = (u16*)p;                 p += (size_t)2048 * 2048 * 2;
    char* aliasb = p;
    u16* Wqd_t   = (u16*)p;                 p += (size_t)1536 * 2048 * 2;
    u16* Wqu_t   = (u16*)p;                 p += (size_t)3072 * 1536 * 2;
    u16* Wkvd_t  = (u16*)p;                 p += (size_t)640  * 2048 * 2;
    u16* Wkvu_t  = (u16*)p;                 p += (size_t)4096 * 512  * 2;
    u16* Wo_t    = (u16*)p;                 p += (size_t)2048 * 2048 * 2;
    float* qd    = (float*)p;               p += (size_t)2048 * 1536 * 4;
    u16* qdb     = (u16*)p;                 p += (size_t)2048 * 1536 * 2;
    u16* qbuf    = (u16*)p;                 p += (size_t)2048 * 3072 * 2;
    float* ckv   = (float*)p;               p += (size_t)2048 * 576  * 4;
    u16* ckvb    = (u16*)p;                 p += (size_t)2048 * 512  * 2;
    u16* kvbf    = (u16*)p;                 p += (size_t)2048 * 4096 * 2;
    u16* krotb   = (u16*)p;                 p += (size_t)2048 * 64   * 2;
    u16* attb    = (u16*)aliasb;            // aliases Wqd_t/Wqu_t (dead before attn)

    dim3 blk(256);
    cast_f32_bf16<<<2048, blk, 0, stream>>>(x, xb);
    tcast_kernel<<<dim3(24, 32), blk, 0, stream>>>(Wq_down, Wqd_t, 2048, 1536, 1.0f);
    tcast_kernel<<<dim3(48, 24), blk, 0, stream>>>(Wq_up,   Wqu_t, 1536, 3072, SCALE); // fold 1/sqrt(dv)
    tcast_kernel<<<dim3(10, 32), blk, 0, stream>>>(Wkv_down, Wkvd_t, 2048, 576, 1.0f);
    tcast_kernel<<<dim3(64, 8),  blk, 0, stream>>>(Wkv_up,  Wkvu_t, 512, 4096, 1.0f);
    tcast_kernel<<<dim3(32, 32), blk, 0, stream>>>(Wo,      Wo_t,  2048, 2048, 1.0f);

    gemm_bf16<false><<<dim3(12, 16), blk, 0, stream>>>(xb, Wqd_t, qd, 2048, 1536, 2048);
    rmsnorm_bf16<<<2048, blk, 0, stream>>>(qd, q_norm_w, qdb, 1536, 1536, 1536);
    gemm_bf16<true><<<dim3(24, 16), blk, 0, stream>>>(qdb, Wqu_t, qbuf, 2048, 3072, 1536);
    gemm_bf16<false><<<dim3(5, 16), blk, 0, stream>>>(xb, Wkvd_t, ckv, 2048, 576, 2048);
    rmsnorm_bf16<<<2048, blk, 0, stream>>>(ckv, kv_norm_w, ckvb, 576, 512, 512);
    gemm_bf16<true><<<dim3(32, 16), blk, 0, stream>>>(ckvb, Wkvu_t, kvbf, 2048, 4096, 512);
    rope_bf16<<<2048, blk, 0, stream>>>(qbuf, ckv, krotb);
    attn_mfma<<<dim3(512), blk, 0, stream>>>(qbuf, kvbf, krotb, attb);
    gemm_bf16<false><<<dim3(16, 16), blk, 0, stream>>>(attb, Wo_t, out, 2048, 2048, 2048);
}

// Round 5
// 246.584 us; speedup vs baseline: 13.9748x; 1.2336x over previous
//
#include <hip/hip_runtime.h>
#include <hip/hip_bf16.h>
#include <cstddef>

#define H 16
#define DN 128
#define DR 64
#define DV 128
#define QLR 1536
#define KVLR 512
#define HID 2048
#define SLEN 2048
#define EPS 1e-6f
#define SCALE 0.08838834764831845f   /* 1/sqrt(128) */

typedef __attribute__((ext_vector_type(8))) short short8;
typedef __attribute__((ext_vector_type(4))) float f32x4;
typedef unsigned short u16;

__device__ __forceinline__ u16 f2bf(float f) {
    __hip_bfloat16 h = __float2bfloat16(f);
    return __builtin_bit_cast(u16, h);
}
__device__ __forceinline__ float b2f(u16 v) {
    return __bfloat162float(__builtin_bit_cast(__hip_bfloat16, v));
}
__device__ __forceinline__ unsigned pack2(float a, float b) {
    return (unsigned)f2bf(a) | ((unsigned)f2bf(b) << 16);
}

// ---------------- elementwise f32 -> bf16 cast ----------------
__global__ __launch_bounds__(256) void cast_f32_bf16(
    const float* __restrict__ in, u16* __restrict__ out)
{
    size_t base = ((size_t)blockIdx.x * 256 + threadIdx.x) * 8;
    float4 v0 = *reinterpret_cast<const float4*>(in + base);
    float4 v1 = *reinterpret_cast<const float4*>(in + base + 4);
    union { short8 s; unsigned u[4]; } p;
    p.u[0] = pack2(v0.x, v0.y); p.u[1] = pack2(v0.z, v0.w);
    p.u[2] = pack2(v1.x, v1.y); p.u[3] = pack2(v1.z, v1.w);
    *reinterpret_cast<short8*>(out + base) = p.s;
}

// ---------------- transpose-cast: W f32 [K][N] -> Wt bf16 [Npad][K], optional scale ----------------
__global__ __launch_bounds__(256) void tcast_kernel(
    const float* __restrict__ W, u16* __restrict__ Wt, int K, int N, float scale)
{
    __shared__ float T[64][65];
    const int tid = threadIdx.x;
    const int n0 = blockIdx.x * 64, k0 = blockIdx.y * 64;
    const bool inb = (n0 < N);
    {
        int r = tid >> 4, c4 = (tid & 15) * 4;
        #pragma unroll
        for (int rr = 0; rr < 4; ++rr) {
            int row = rr * 16 + r;
            float4 v = inb ? *reinterpret_cast<const float4*>(W + (size_t)(k0 + row) * N + n0 + c4)
                           : make_float4(0.f, 0.f, 0.f, 0.f);
            T[row][c4] = v.x * scale; T[row][c4 + 1] = v.y * scale;
            T[row][c4 + 2] = v.z * scale; T[row][c4 + 3] = v.w * scale;
        }
    }
    __syncthreads();
    {
        int n = tid >> 2, kq = (tid & 3) * 16;
        unsigned u[8];
        #pragma unroll
        for (int jj = 0; jj < 8; ++jj)
            u[jj] = pack2(T[kq + 2 * jj][n], T[kq + 2 * jj + 1][n]);
        u16* dst = Wt + (size_t)(n0 + n) * K + k0 + kq;
        *reinterpret_cast<uint4*>(dst)     = make_uint4(u[0], u[1], u[2], u[3]);
        *reinterpret_cast<uint4*>(dst + 8) = make_uint4(u[4], u[5], u[6], u[7]);
    }
}

// ---------------- bf16 MFMA GEMM: C[M,N] = A[M,K] @ Bt[Npad,K]^T ----------------
__device__ __forceinline__ void stage4(const char* Gb, const unsigned* srcOff,
                                       const int* ldsBase, u16* smemBuf, unsigned koff)
{
    #pragma unroll
    for (int j = 0; j < 4; ++j)
        __builtin_amdgcn_global_load_lds(
            (const __attribute__((address_space(1))) unsigned int*)(Gb + srcOff[j] + koff),
            (__attribute__((address_space(3))) unsigned int*)(smemBuf + ldsBase[j]),
            16, 0, 0);
}

template<bool BF16OUT>
__global__ __launch_bounds__(256) void gemm_bf16(
    const u16* __restrict__ A, const u16* __restrict__ Bt,
    void* __restrict__ Cv, int M, int N, int K)
{
    __shared__ u16 smem[2][8192];
    const int tid = threadIdx.x, lane = tid & 63, w = tid >> 6;

    // bijective XCD-chunked swizzle; by-fastest so one XCD reuses a B-panel
    const int nbx = gridDim.x, nby = gridDim.y;
    const int nwg = nbx * nby;
    int orig = blockIdx.y * nbx + blockIdx.x;
    int xcd = orig & 7, o8 = orig >> 3;
    int qq = nwg >> 3, rr = nwg & 7;
    int v = (xcd < rr ? xcd * (qq + 1) : rr * (qq + 1) + (xcd - rr) * qq) + o8;
    int bx = v / nby, by = v - bx * nby;
    const int m0 = by * 128, n0 = bx * 128;
    const size_t Kb = (size_t)K * 2;

    unsigned srcOff[4];
    int ldsBase[4];
    #pragma unroll
    for (int j = 0; j < 4; ++j) {
        int c = w * 4 + j;
        int o = (c & 7) * 1024 + lane * 16;
        int u = o ^ (((o >> 7) & 3) << 4);
        int row = u >> 6, kbyte = u & 63;
        srcOff[j] = (unsigned)((size_t)((c < 8 ? m0 : n0) + row) * Kb + kbyte);
        ldsBase[j] = (c < 8) ? (c * 512) : (4096 + (c - 8) * 512);
    }
    const char* Gb = (w < 2) ? (const char*)A : (const char*)Bt;

    const int wr = (w >> 1) * 64, wc = (w & 1) * 64;
    int aoff[4], boff[4];
    #pragma unroll
    for (int i = 0; i < 4; ++i) {
        int oa = (wr + i * 16 + (lane & 15)) * 64 + (lane >> 4) * 16;
        aoff[i] = oa ^ (((oa >> 7) & 3) << 4);
        int ob = (wc + i * 16 + (lane & 15)) * 64 + (lane >> 4) * 16;
        boff[i] = (ob ^ (((ob >> 7) & 3) << 4)) + 8192;
    }

    f32x4 acc[4][4];
    #pragma unroll
    for (int i = 0; i < 4; ++i)
        #pragma unroll
        for (int j = 0; j < 4; ++j) acc[i][j] = (f32x4){0.f, 0.f, 0.f, 0.f};

    const int NT = K >> 5;
    stage4(Gb, srcOff, ldsBase, &smem[0][0], 0);
    __syncthreads();
    int cur = 0;
    for (int t = 0; t < NT; ++t) {
        if (t + 1 < NT) stage4(Gb, srcOff, ldsBase, &smem[cur ^ 1][0], (unsigned)(t + 1) * 64);
        const char* base = (const char*)&smem[cur][0];
        short8 af[4], bfr[4];
        #pragma unroll
        for (int i = 0; i < 4; ++i) af[i] = *reinterpret_cast<const short8*>(base + aoff[i]);
        #pragma unroll
        for (int i = 0; i < 4; ++i) bfr[i] = *reinterpret_cast<const short8*>(base + boff[i]);
        __builtin_amdgcn_s_setprio(1);
        #pragma unroll
        for (int i = 0; i < 4; ++i)
            #pragma unroll
            for (int j = 0; j < 4; ++j)
                acc[i][j] = __builtin_amdgcn_mfma_f32_16x16x32_bf16(af[i], bfr[j], acc[i][j], 0, 0, 0);
        __builtin_amdgcn_s_setprio(0);
        __syncthreads();
        cur ^= 1;
    }

    #pragma unroll
    for (int i = 0; i < 4; ++i) {
        int grow0 = m0 + wr + i * 16 + ((lane >> 4) * 4);
        #pragma unroll
        for (int j = 0; j < 4; ++j) {
            int gcol = n0 + wc + j * 16 + (lane & 15);
            if (gcol < N) {
                #pragma unroll
                for (int r = 0; r < 4; ++r) {
                    float v2 = acc[i][j][r];
                    if (BF16OUT) ((u16*)Cv)[(size_t)(grow0 + r) * N + gcol] = f2bf(v2);
                    else         ((float*)Cv)[(size_t)(grow0 + r) * N + gcol] = v2;
                }
            }
        }
    }
}

// ---------------- RMSNorm: fp32 in (strided) -> bf16 out ----------------
__global__ __launch_bounds__(256) void rmsnorm_bf16(
    const float* __restrict__ in, const float* __restrict__ wgt,
    u16* __restrict__ out, int inStride, int outStride, int D)
{
    const int row = blockIdx.x, tid = threadIdx.x;
    const float* p = in + (size_t)row * inStride;
    float ss = 0.f;
    for (int i = tid * 4; i < D; i += 1024) {
        float4 v = *reinterpret_cast<const float4*>(p + i);
        ss += v.x * v.x + v.y * v.y + v.z * v.z + v.w * v.w;
    }
    __shared__ float wsum[4];
    int lane = tid & 63, wv = tid >> 6;
    #pragma unroll
    for (int off = 32; off; off >>= 1) ss += __shfl_down(ss, off);
    if (lane == 0) wsum[wv] = ss;
    __syncthreads();
    if (tid == 0) {
        float t = wsum[0] + wsum[1] + wsum[2] + wsum[3];
        wsum[0] = rsqrtf(t / (float)D + EPS);
    }
    __syncthreads();
    float sc = wsum[0];
    for (int i = tid * 4; i < D; i += 1024) {
        float4 v = *reinterpret_cast<const float4*>(p + i);
        float4 g = *reinterpret_cast<const float4*>(wgt + i);
        unsigned lo = pack2(v.x * sc * g.x, v.y * sc * g.y);
        unsigned hi = pack2(v.z * sc * g.z, v.w * sc * g.w);
        *reinterpret_cast<uint2*>(out + (size_t)row * outStride + i) = make_uint2(lo, hi);
    }
}

// ---------------- RoPE in place on bf16 q + krot from f32 (strided) ----------------
__global__ __launch_bounds__(256) void rope_bf16(
    u16* __restrict__ q, const float* __restrict__ krsrc, int krStride,
    u16* __restrict__ krot)
{
    const int s = blockIdx.x, tid = threadIdx.x;
    __shared__ float cs[32], sn[32];
    if (tid < 32) {
        float inv = powf(10000.0f, -(float)tid / 32.0f);
        float ang = (float)s * inv;
        cs[tid] = cosf(ang); sn[tid] = sinf(ang);
    }
    __syncthreads();
    float ev[2], ov[2]; int hh[2], ii[2];
    #pragma unroll
    for (int it = 0; it < 2; ++it) {
        int pidx = tid + it * 256;
        int h = pidx >> 5, i = pidx & 31;
        hh[it] = h; ii[it] = i;
        const u16* base = q + (size_t)s * 3072 + h * 192 + 128;
        ev[it] = b2f(base[2 * i]); ov[it] = b2f(base[2 * i + 1]);
    }
    __syncthreads();
    #pragma unroll
    for (int it = 0; it < 2; ++it) {
        int h = hh[it], i = ii[it];
        u16* base = q + (size_t)s * 3072 + h * 192 + 128;
        base[i]      = f2bf(ev[it] * cs[i] - ov[it] * sn[i]);
        base[32 + i] = f2bf(ov[it] * cs[i] + ev[it] * sn[i]);
    }
    if (tid < 32) {
        int i = tid;
        float e = krsrc[(size_t)s * krStride + 2 * i];
        float o = krsrc[(size_t)s * krStride + 2 * i + 1];
        krot[(size_t)s * 64 + i]      = f2bf(e * cs[i] - o * sn[i]);
        krot[(size_t)s * 64 + 32 + i] = f2bf(o * cs[i] + e * sn[i]);
    }
}

// ---------------- MFMA flash attention: KB=64, single LDS buffer, 2 barriers/tile ----------------
// 512 blocks XCD-mapped; 256 threads = 4 waves x 16 q-rows.
__global__ __launch_bounds__(256, 2) void attn_mfma(
    const u16* __restrict__ qbf,   // [S][H][192]  (rope applied, pre-scaled)
    const u16* __restrict__ kvbf,  // [S][H][256]  (k_nope | v)
    const u16* __restrict__ krot,  // [S][64]
    u16* __restrict__ outb)        // [S][2048] bf16
{
    const int bid = blockIdx.x;
    const int xcd = bid & 7, slot = bid >> 3;
    const int h = xcd + 8 * (slot >> 5);
    const int inner = slot & 31;
    const int qb = (inner & 1) ? (31 - (inner >> 1)) : (inner >> 1);
    const int s0 = qb * 64;
    const int tid = threadIdx.x, lane = tid & 63, w = tid >> 6;

    __shared__ u16 Ks[64 * 200];   // [key][192+pad8]
    __shared__ u16 Vt[128 * 72];   // physical row = (d>>1) + (d&1)*64, col = key (+pad8)
    __shared__ u16 Ps[64 * 72];    // [qrow][64 keys + pad8]

    const int colk = lane & 15;
    const int g8 = (lane >> 4) * 8;

    // Q fragments (rows w*16..w*16+15), pre-scaled by SCALE via Wq_up fold
    short8 qreg[6];
    {
        const u16* qp = qbf + ((size_t)(s0 + w * 16 + colk) * H + h) * 192;
        #pragma unroll
        for (int ks = 0; ks < 6; ++ks)
            qreg[ks] = *reinterpret_cast<const short8*>(qp + ks * 32 + g8);
    }

    // staging geometry
    int kt[6], kd0[6];
    #pragma unroll
    for (int it = 0; it < 6; ++it) {
        int c = it * 256 + tid;
        kt[it] = c / 24; kd0[it] = (c % 24) * 8;
    }
    int vd2[2], vt8[2];
    #pragma unroll
    for (int it = 0; it < 2; ++it) {
        int c = it * 256 + tid;
        vd2[it] = c & 63; vt8[it] = c >> 6;     // d-pair index, key-chunk (8 keys)
    }

    short8 kreg[6];
    unsigned vreg[2][8];

    auto issue_loads = [&](int kb) {
        #pragma unroll
        for (int it = 0; it < 6; ++it) {
            int gk = kb * 64 + kt[it];
            const u16* src = (kd0[it] < 128)
                ? kvbf + ((size_t)gk * H + h) * 256 + kd0[it]
                : krot + (size_t)gk * 64 + (kd0[it] - 128);
            kreg[it] = *reinterpret_cast<const short8*>(src);
        }
        #pragma unroll
        for (int it = 0; it < 2; ++it)
            #pragma unroll
            for (int j = 0; j < 8; ++j)
                vreg[it][j] = *reinterpret_cast<const unsigned*>(
                    kvbf + ((size_t)(kb * 64 + vt8[it] * 8 + j) * H + h) * 256 + 128 + 2 * vd2[it]);
    };
    auto write_lds = [&]() {
        #pragma unroll
        for (int it = 0; it < 6; ++it)
            *reinterpret_cast<short8*>(&Ks[kt[it] * 200 + kd0[it]]) = kreg[it];
        #pragma unroll
        for (int it = 0; it < 2; ++it) {
            uint4 lo, hi;
            unsigned* lp = &lo.x; unsigned* hp = &hi.x;
            #pragma unroll
            for (int p2 = 0; p2 < 4; ++p2) {
                unsigned a = vreg[it][2 * p2], b = vreg[it][2 * p2 + 1];
                lp[p2] = (a & 0xffffu) | (b << 16);
                hp[p2] = (a >> 16) | (b & 0xffff0000u);
            }
            *reinterpret_cast<uint4*>(&Vt[vd2[it] * 72 + vt8[it] * 8]) = lo;         // d even
            *reinterpret_cast<uint4*>(&Vt[(64 + vd2[it]) * 72 + vt8[it] * 8]) = hi;  // d odd
        }
    };

    float m_run[4] = {-1e30f, -1e30f, -1e30f, -1e30f};
    float l_run[4] = {0.f, 0.f, 0.f, 0.f};   // per-lane partial sums
    f32x4 acc_o[8];
    #pragma unroll
    for (int i = 0; i < 8; ++i) acc_o[i] = (f32x4){0.f, 0.f, 0.f, 0.f};

    const int nkt = qb + 1;
    issue_loads(0);

    for (int kb = 0; kb < nkt; ++kb) {
        __syncthreads();               // (A) all waves done reading previous tile
        write_lds();                   // waits on this tile's global loads (vmcnt)
        __syncthreads();               // (B) LDS tile ready
        if (kb + 1 < nkt) issue_loads(kb + 1);   // overlaps compute below

        // QK^T: 4 col-tiles x 6 k-steps
        f32x4 sacc[4];
        #pragma unroll
        for (int ct = 0; ct < 4; ++ct) sacc[ct] = (f32x4){0.f, 0.f, 0.f, 0.f};
        __builtin_amdgcn_s_setprio(1);
        #pragma unroll
        for (int ks = 0; ks < 6; ++ks) {
            #pragma unroll
            for (int ct = 0; ct < 4; ++ct) {
                short8 b = *reinterpret_cast<const short8*>(
                    &Ks[(ct * 16 + colk) * 200 + ks * 32 + g8]);
                sacc[ct] = __builtin_amdgcn_mfma_f32_16x16x32_bf16(qreg[ks], b, sacc[ct], 0, 0, 0);
            }
        }
        __builtin_amdgcn_s_setprio(0);

        // online softmax; rows wave-private; only last tile needs causal mask
        const bool lastTile = (kb == nkt - 1);
        float sv[4][4], mx[4];
        #pragma unroll
        for (int r = 0; r < 4; ++r) {
            int qg = s0 + w * 16 + (lane >> 4) * 4 + r;
            #pragma unroll
            for (int ct = 0; ct < 4; ++ct) {
                float val = sacc[ct][r];
                if (lastTile) {
                    int key = kb * 64 + ct * 16 + colk;
                    val = (key <= qg) ? val : -1e30f;
                }
                sv[r][ct] = val;
            }
            float m = fmaxf(fmaxf(sv[r][0], sv[r][1]), fmaxf(sv[r][2], sv[r][3]));
            m = fmaxf(m, __shfl_xor(m, 1));
            m = fmaxf(m, __shfl_xor(m, 2));
            m = fmaxf(m, __shfl_xor(m, 4));
            m = fmaxf(m, __shfl_xor(m, 8));
            mx[r] = m;
        }
        bool small = (mx[0] <= m_run[0] + 8.f) && (mx[1] <= m_run[1] + 8.f) &&
                     (mx[2] <= m_run[2] + 8.f) && (mx[3] <= m_run[3] + 8.f);
        if (!__all(small)) {
            #pragma unroll
            for (int r = 0; r < 4; ++r) {
                float mnew = fmaxf(m_run[r], mx[r]);
                float f = __expf(m_run[r] - mnew);
                m_run[r] = mnew;
                l_run[r] *= f;
                #pragma unroll
                for (int ct = 0; ct < 8; ++ct) acc_o[ct][r] *= f;
            }
        }
        #pragma unroll
        for (int r = 0; r < 4; ++r) {
            int prow = w * 16 + (lane >> 4) * 4 + r;
            float psum = 0.f;
            #pragma unroll
            for (int ct = 0; ct < 4; ++ct) {
                float pz = __expf(sv[r][ct] - m_run[r]);
                Ps[prow * 72 + ct * 16 + colk] = f2bf(pz);
                psum += pz;
            }
            l_run[r] += psum;   // per-lane partial; reduced once at the end
        }

        // PV: O[16x128] += P[16x64] @ V[64x128]
        __builtin_amdgcn_s_setprio(1);
        #pragma unroll
        for (int ks2 = 0; ks2 < 2; ++ks2) {
            short8 pa = *reinterpret_cast<const short8*>(
                &Ps[(w * 16 + colk) * 72 + ks2 * 32 + g8]);
            #pragma unroll
            for (int ct = 0; ct < 8; ++ct) {
                int c = ct * 16 + colk;
                int phys = (c >> 1) + (c & 1) * 64;
                short8 vb = *reinterpret_cast<const short8*>(
                    &Vt[phys * 72 + ks2 * 32 + g8]);
                acc_o[ct] = __builtin_amdgcn_mfma_f32_16x16x32_bf16(pa, vb, acc_o[ct], 0, 0, 0);
            }
        }
        __builtin_amdgcn_s_setprio(0);
    }

    // epilogue: final l reduction across the 16 key-lanes, normalize, store
    #pragma unroll
    for (int r = 0; r < 4; ++r) {
        float l = l_run[r];
        l += __shfl_xor(l, 1);
        l += __shfl_xor(l, 2);
        l += __shfl_xor(l, 4);
        l += __shfl_xor(l, 8);
        float invl = 1.0f / l;
        int row = s0 + w * 16 + (lane >> 4) * 4 + r;
        #pragma unroll
        for (int ct = 0; ct < 8; ++ct)
            outb[(size_t)row * 2048 + h * 128 + ct * 16 + colk] = f2bf(acc_o[ct][r] * invl);
    }
}

extern "C" void kernel_launch(void* const* d_in, const int* in_sizes, int n_in,
                              void* d_out, int out_size, void* d_ws, size_t ws_size,
                              hipStream_t stream)
{
    (void)in_sizes; (void)n_in; (void)out_size; (void)ws_size;
    const float* x         = (const float*)d_in[0];
    const float* Wq_down   = (const float*)d_in[1];
    const float* q_norm_w  = (const float*)d_in[2];
    const float* Wq_up     = (const float*)d_in[3];
    const float* Wkv_down  = (const float*)d_in[4];
    const float* kv_norm_w = (const float*)d_in[5];
    const float* Wkv_up    = (const float*)d_in[6];
    const float* Wo        = (const float*)d_in[7];
    float* out = (float*)d_out;

    char* p = (char*)d_ws;
    u16* xb      = (u16*)p;                 p += (size_t)2048 * 2048 * 2;   // 8 MB
    char* aliasb = p;
    u16* BtF     = (u16*)p;                 p += (size_t)2176 * 2048 * 2;   // fused [Wqd|Wkvd]^T
    u16* Wqu_t   = (u16*)p;                 p += (size_t)3072 * 1536 * 2;
    u16* Wkvu_t  = (u16*)p;                 p += (size_t)4096 * 512  * 2;
    u16* Wo_t    = (u16*)p;                 p += (size_t)2048 * 2048 * 2;
    float* fC    = (float*)p;               p += (size_t)2048 * 2112 * 4;   // fused down-proj out
    u16* qdb     = (u16*)p;                 p += (size_t)2048 * 1536 * 2;
    u16* qbuf    = (u16*)p;                 p += (size_t)2048 * 3072 * 2;
    u16* ckvb    = (u16*)p;                 p += (size_t)2048 * 512  * 2;
    u16* kvbf    = (u16*)p;                 p += (size_t)2048 * 4096 * 2;
    u16* krotb   = (u16*)p;                 p += (size_t)2048 * 64   * 2;
    u16* attb    = (u16*)aliasb;            // aliases BtF (dead before attn)

    dim3 blk(256);
    cast_f32_bf16<<<2048, blk, 0, stream>>>(x, xb);
    tcast_kernel<<<dim3(24, 32), blk, 0, stream>>>(Wq_down, BtF, 2048, 1536, 1.0f);
    tcast_kernel<<<dim3(10, 32), blk, 0, stream>>>(Wkv_down, BtF + (size_t)1536 * 2048, 2048, 576, 1.0f);
    tcast_kernel<<<dim3(48, 24), blk, 0, stream>>>(Wq_up,  Wqu_t, 1536, 3072, SCALE);
    tcast_kernel<<<dim3(64, 8),  blk, 0, stream>>>(Wkv_up, Wkvu_t, 512, 4096, 1.0f);
    tcast_kernel<<<dim3(32, 32), blk, 0, stream>>>(Wo,     Wo_t,  2048, 2048, 1.0f);

    // fused down-proj: [x][Wq_down | Wkv_down] -> fC [2048][2112]
    gemm_bf16<false><<<dim3(17, 16), blk, 0, stream>>>(xb, BtF, fC, 2048, 2112, 2048);
    rmsnorm_bf16<<<2048, blk, 0, stream>>>(fC, q_norm_w, qdb, 2112, 1536, 1536);
    gemm_bf16<true><<<dim3(24, 16), blk, 0, stream>>>(qdb, Wqu_t, qbuf, 2048, 3072, 1536);
    rmsnorm_bf16<<<2048, blk, 0, stream>>>(fC + 1536, kv_norm_w, ckvb, 2112, 512, 512);
    gemm_bf16<true><<<dim3(32, 16), blk, 0, stream>>>(ckvb, Wkvu_t, kvbf, 2048, 4096, 512);
    rope_bf16<<<2048, blk, 0, stream>>>(qbuf, fC + 2048, 2112, krotb);
    attn_mfma<<<dim3(512), blk, 0, stream>>>(qbuf, kvbf, krotb, attb);
    gemm_bf16<false><<<dim3(16, 16), blk, 0, stream>>>(attb, Wo_t, out, 2048, 2048, 2048);
}

// Round 6
// 238.117 us; speedup vs baseline: 14.4717x; 1.0356x over previous
//
#include <hip/hip_runtime.h>
#include <hip/hip_bf16.h>
#include <cstddef>

#define H 16
#define DN 128
#define DR 64
#define DV 128
#define QLR 1536
#define KVLR 512
#define HID 2048
#define SLEN 2048
#define EPS 1e-6f
#define SCALE 0.08838834764831845f   /* 1/sqrt(128) */

typedef __attribute__((ext_vector_type(8))) short short8;
typedef __attribute__((ext_vector_type(4))) float f32x4;
typedef unsigned short u16;

__device__ __forceinline__ u16 f2bf(float f) {
    __hip_bfloat16 h = __float2bfloat16(f);
    return __builtin_bit_cast(u16, h);
}
__device__ __forceinline__ float b2f(u16 v) {
    return __bfloat162float(__builtin_bit_cast(__hip_bfloat16, v));
}
__device__ __forceinline__ unsigned pack2(float a, float b) {
    return (unsigned)f2bf(a) | ((unsigned)f2bf(b) << 16);
}

// ---------------- elementwise f32 -> bf16 cast ----------------
__global__ __launch_bounds__(256) void cast_f32_bf16(
    const float* __restrict__ in, u16* __restrict__ out)
{
    size_t base = ((size_t)blockIdx.x * 256 + threadIdx.x) * 8;
    float4 v0 = *reinterpret_cast<const float4*>(in + base);
    float4 v1 = *reinterpret_cast<const float4*>(in + base + 4);
    union { short8 s; unsigned u[4]; } p;
    p.u[0] = pack2(v0.x, v0.y); p.u[1] = pack2(v0.z, v0.w);
    p.u[2] = pack2(v1.x, v1.y); p.u[3] = pack2(v1.z, v1.w);
    *reinterpret_cast<short8*>(out + base) = p.s;
}

// ---------------- fused transpose-cast of all 5 weights ----------------
__global__ __launch_bounds__(256) void tcast_all(
    const float* __restrict__ Wqd, const float* __restrict__ Wkvd,
    const float* __restrict__ Wqu, const float* __restrict__ Wkvu,
    const float* __restrict__ Wo,
    u16* __restrict__ BtF, u16* __restrict__ Wqu_t,
    u16* __restrict__ Wkvu_t, u16* __restrict__ Wo_t)
{
    int b = blockIdx.x;
    const float* W; u16* Wt; int K, N, nx; float scale = 1.0f;
    if (b < 768)       { W = Wqd;  Wt = BtF;                          K = 2048; N = 1536; nx = 24; }
    else if (b < 1088) { b -= 768;  W = Wkvd; Wt = BtF + (size_t)1536 * 2048; K = 2048; N = 576;  nx = 10; }
    else if (b < 2240) { b -= 1088; W = Wqu;  Wt = Wqu_t;             K = 1536; N = 3072; nx = 48; scale = SCALE; }
    else if (b < 2752) { b -= 2240; W = Wkvu; Wt = Wkvu_t;            K = 512;  N = 4096; nx = 64; }
    else               { b -= 2752; W = Wo;   Wt = Wo_t;              K = 2048; N = 2048; nx = 32; }
    const int bx = b % nx, by = b / nx;

    __shared__ float T[64][65];
    const int tid = threadIdx.x;
    const int n0 = bx * 64, k0 = by * 64;
    const bool inb = (n0 < N);
    {
        int r = tid >> 4, c4 = (tid & 15) * 4;
        #pragma unroll
        for (int rr = 0; rr < 4; ++rr) {
            int row = rr * 16 + r;
            float4 v = inb ? *reinterpret_cast<const float4*>(W + (size_t)(k0 + row) * N + n0 + c4)
                           : make_float4(0.f, 0.f, 0.f, 0.f);
            T[row][c4] = v.x * scale; T[row][c4 + 1] = v.y * scale;
            T[row][c4 + 2] = v.z * scale; T[row][c4 + 3] = v.w * scale;
        }
    }
    __syncthreads();
    {
        int n = tid >> 2, kq = (tid & 3) * 16;
        unsigned u[8];
        #pragma unroll
        for (int jj = 0; jj < 8; ++jj)
            u[jj] = pack2(T[kq + 2 * jj][n], T[kq + 2 * jj + 1][n]);
        u16* dst = Wt + (size_t)(n0 + n) * K + k0 + kq;
        *reinterpret_cast<uint4*>(dst)     = make_uint4(u[0], u[1], u[2], u[3]);
        *reinterpret_cast<uint4*>(dst + 8) = make_uint4(u[4], u[5], u[6], u[7]);
    }
}

// ---------------- bf16 MFMA GEMM: C[M,N] = A[M,K] @ Bt[Npad,K]^T ----------------
__device__ __forceinline__ void stage4(const char* Gb, const unsigned* srcOff,
                                       const int* ldsBase, u16* smemBuf, unsigned koff)
{
    #pragma unroll
    for (int j = 0; j < 4; ++j)
        __builtin_amdgcn_global_load_lds(
            (const __attribute__((address_space(1))) unsigned int*)(Gb + srcOff[j] + koff),
            (__attribute__((address_space(3))) unsigned int*)(smemBuf + ldsBase[j]),
            16, 0, 0);
}

template<bool BF16OUT>
__global__ __launch_bounds__(256) void gemm_bf16(
    const u16* __restrict__ A, const u16* __restrict__ Bt,
    void* __restrict__ Cv, int M, int N, int K)
{
    __shared__ u16 smem[2][8192];
    const int tid = threadIdx.x, lane = tid & 63, w = tid >> 6;

    const int nbx = gridDim.x, nby = gridDim.y;
    const int nwg = nbx * nby;
    int orig = blockIdx.y * nbx + blockIdx.x;
    int xcd = orig & 7, o8 = orig >> 3;
    int qq = nwg >> 3, rr = nwg & 7;
    int v = (xcd < rr ? xcd * (qq + 1) : rr * (qq + 1) + (xcd - rr) * qq) + o8;
    int bx = v / nby, by = v - bx * nby;
    const int m0 = by * 128, n0 = bx * 128;
    const size_t Kb = (size_t)K * 2;

    unsigned srcOff[4];
    int ldsBase[4];
    #pragma unroll
    for (int j = 0; j < 4; ++j) {
        int c = w * 4 + j;
        int o = (c & 7) * 1024 + lane * 16;
        int u = o ^ (((o >> 7) & 3) << 4);
        int row = u >> 6, kbyte = u & 63;
        srcOff[j] = (unsigned)((size_t)((c < 8 ? m0 : n0) + row) * Kb + kbyte);
        ldsBase[j] = (c < 8) ? (c * 512) : (4096 + (c - 8) * 512);
    }
    const char* Gb = (w < 2) ? (const char*)A : (const char*)Bt;

    const int wr = (w >> 1) * 64, wc = (w & 1) * 64;
    int aoff[4], boff[4];
    #pragma unroll
    for (int i = 0; i < 4; ++i) {
        int oa = (wr + i * 16 + (lane & 15)) * 64 + (lane >> 4) * 16;
        aoff[i] = oa ^ (((oa >> 7) & 3) << 4);
        int ob = (wc + i * 16 + (lane & 15)) * 64 + (lane >> 4) * 16;
        boff[i] = (ob ^ (((ob >> 7) & 3) << 4)) + 8192;
    }

    f32x4 acc[4][4];
    #pragma unroll
    for (int i = 0; i < 4; ++i)
        #pragma unroll
        for (int j = 0; j < 4; ++j) acc[i][j] = (f32x4){0.f, 0.f, 0.f, 0.f};

    const int NT = K >> 5;
    stage4(Gb, srcOff, ldsBase, &smem[0][0], 0);
    __syncthreads();
    int cur = 0;
    for (int t = 0; t < NT; ++t) {
        if (t + 1 < NT) stage4(Gb, srcOff, ldsBase, &smem[cur ^ 1][0], (unsigned)(t + 1) * 64);
        const char* base = (const char*)&smem[cur][0];
        short8 af[4], bfr[4];
        #pragma unroll
        for (int i = 0; i < 4; ++i) af[i] = *reinterpret_cast<const short8*>(base + aoff[i]);
        #pragma unroll
        for (int i = 0; i < 4; ++i) bfr[i] = *reinterpret_cast<const short8*>(base + boff[i]);
        __builtin_amdgcn_s_setprio(1);
        #pragma unroll
        for (int i = 0; i < 4; ++i)
            #pragma unroll
            for (int j = 0; j < 4; ++j)
                acc[i][j] = __builtin_amdgcn_mfma_f32_16x16x32_bf16(af[i], bfr[j], acc[i][j], 0, 0, 0);
        __builtin_amdgcn_s_setprio(0);
        __syncthreads();
        cur ^= 1;
    }

    #pragma unroll
    for (int i = 0; i < 4; ++i) {
        int grow0 = m0 + wr + i * 16 + ((lane >> 4) * 4);
        #pragma unroll
        for (int j = 0; j < 4; ++j) {
            int gcol = n0 + wc + j * 16 + (lane & 15);
            if (gcol < N) {
                #pragma unroll
                for (int r = 0; r < 4; ++r) {
                    float v2 = acc[i][j][r];
                    if (BF16OUT) ((u16*)Cv)[(size_t)(grow0 + r) * N + gcol] = f2bf(v2);
                    else         ((float*)Cv)[(size_t)(grow0 + r) * N + gcol] = v2;
                }
            }
        }
    }
}

// ---------------- RMSNorm: fp32 in (strided) -> bf16 out ----------------
__global__ __launch_bounds__(256) void rmsnorm_bf16(
    const float* __restrict__ in, const float* __restrict__ wgt,
    u16* __restrict__ out, int inStride, int outStride, int D)
{
    const int row = blockIdx.x, tid = threadIdx.x;
    const float* p = in + (size_t)row * inStride;
    float ss = 0.f;
    for (int i = tid * 4; i < D; i += 1024) {
        float4 v = *reinterpret_cast<const float4*>(p + i);
        ss += v.x * v.x + v.y * v.y + v.z * v.z + v.w * v.w;
    }
    __shared__ float wsum[4];
    int lane = tid & 63, wv = tid >> 6;
    #pragma unroll
    for (int off = 32; off; off >>= 1) ss += __shfl_down(ss, off);
    if (lane == 0) wsum[wv] = ss;
    __syncthreads();
    if (tid == 0) {
        float t = wsum[0] + wsum[1] + wsum[2] + wsum[3];
        wsum[0] = rsqrtf(t / (float)D + EPS);
    }
    __syncthreads();
    float sc = wsum[0];
    for (int i = tid * 4; i < D; i += 1024) {
        float4 v = *reinterpret_cast<const float4*>(p + i);
        float4 g = *reinterpret_cast<const float4*>(wgt + i);
        unsigned lo = pack2(v.x * sc * g.x, v.y * sc * g.y);
        unsigned hi = pack2(v.z * sc * g.z, v.w * sc * g.w);
        *reinterpret_cast<uint2*>(out + (size_t)row * outStride + i) = make_uint2(lo, hi);
    }
}

// ---------------- RoPE in place on bf16 q + krot from f32 (strided) ----------------
__global__ __launch_bounds__(256) void rope_bf16(
    u16* __restrict__ q, const float* __restrict__ krsrc, int krStride,
    u16* __restrict__ krot)
{
    const int s = blockIdx.x, tid = threadIdx.x;
    __shared__ float cs[32], sn[32];
    if (tid < 32) {
        float inv = powf(10000.0f, -(float)tid / 32.0f);
        float ang = (float)s * inv;
        cs[tid] = cosf(ang); sn[tid] = sinf(ang);
    }
    __syncthreads();
    float ev[2], ov[2]; int hh[2], ii[2];
    #pragma unroll
    for (int it = 0; it < 2; ++it) {
        int pidx = tid + it * 256;
        int h = pidx >> 5, i = pidx & 31;
        hh[it] = h; ii[it] = i;
        const u16* base = q + (size_t)s * 3072 + h * 192 + 128;
        ev[it] = b2f(base[2 * i]); ov[it] = b2f(base[2 * i + 1]);
    }
    __syncthreads();
    #pragma unroll
    for (int it = 0; it < 2; ++it) {
        int h = hh[it], i = ii[it];
        u16* base = q + (size_t)s * 3072 + h * 192 + 128;
        base[i]      = f2bf(ev[it] * cs[i] - ov[it] * sn[i]);
        base[32 + i] = f2bf(ov[it] * cs[i] + ev[it] * sn[i]);
    }
    if (tid < 32) {
        int i = tid;
        float e = krsrc[(size_t)s * krStride + 2 * i];
        float o = krsrc[(size_t)s * krStride + 2 * i + 1];
        krot[(size_t)s * 64 + i]      = f2bf(e * cs[i] - o * sn[i]);
        krot[(size_t)s * 64 + 32 + i] = f2bf(o * cs[i] + e * sn[i]);
    }
}

// ---------------- split-K flash attention chunk kernel ----------------
// 1280 blocks (XCD-mapped); 256 thr = 4 waves; KB=64/tile; <=8 tiles (512 keys)/chunk.
// Chunks with S>1 write fp32 partials; S==1 writes final bf16 directly.
__global__ __launch_bounds__(256, 2) void attn_chunk(
    const u16* __restrict__ qbf,   // [S][H][192]
    const u16* __restrict__ kvbf,  // [S][H][256]
    const u16* __restrict__ krot,  // [S][64]
    u16* __restrict__ outb,        // [S][2048]
    float* __restrict__ partAcc,   // [1152][64][128]
    float* __restrict__ partML)    // [1152][64][2]
{
    const int bid = blockIdx.x;
    const int xcd = bid & 7, slot = bid >> 3;       // slot 0..159
    const int h = xcd + 8 * (slot / 80);
    const int r80 = slot % 80;
    int qb, ch, S, poff;
    if (r80 < 8)       { qb = r80;                 ch = 0;      S = 1; poff = 0; }
    else if (r80 < 24) { int u = r80 - 8;  qb = 8 + (u >> 1);  ch = u & 1; S = 2; poff = (qb - 8) * 2 + ch; }
    else if (r80 < 48) { int u = r80 - 24; qb = 16 + u / 3;    ch = u % 3; S = 3; poff = 16 + (qb - 16) * 3 + ch; }
    else               { int u = r80 - 48; qb = 24 + (u >> 2); ch = u & 3; S = 4; poff = 40 + (qb - 24) * 4 + ch; }
    const int s0 = qb * 64;
    const int t0 = ch * 8;
    const int t1 = (t0 + 8 < qb + 1) ? (t0 + 8) : (qb + 1);
    const int slotId = h * 72 + poff;
    const int tid = threadIdx.x, lane = tid & 63, w = tid >> 6;
    const int colk = lane & 15, grp = lane >> 4, g8 = grp * 8;

    __shared__ u16 Ks[64 * 192];   // row stride 192 u16, 16B slots XOR'd by (key&7)
    __shared__ u16 Vt[128 * 64];   // phys row=(d>>1)+(d&1)*64, slots XOR'd by (phys&7)
    __shared__ u16 Ps[64 * 64];    // row stride 64 u16, slots XOR'd by (row&7)

    // Q fragments (pre-scaled via Wq_up fold)
    short8 qreg[6];
    {
        const u16* qp = qbf + ((size_t)(s0 + w * 16 + colk) * H + h) * 192;
        #pragma unroll
        for (int ks = 0; ks < 6; ++ks)
            qreg[ks] = *reinterpret_cast<const short8*>(qp + ks * 32 + g8);
    }

    // staging geometry
    int kt[6], kslot[6];
    #pragma unroll
    for (int it = 0; it < 6; ++it) {
        int c = it * 256 + tid;
        kt[it] = c / 24; kslot[it] = c % 24;
    }
    int vd2[2], vt8[2];
    #pragma unroll
    for (int it = 0; it < 2; ++it) {
        int c = it * 256 + tid;
        vd2[it] = c & 63; vt8[it] = c >> 6;
    }

    short8 kreg[6];
    unsigned vreg[2][8];

    auto issue_loads = [&](int t) {
        #pragma unroll
        for (int it = 0; it < 6; ++it) {
            int gk = t * 64 + kt[it];
            const u16* src = (kslot[it] < 16)
                ? kvbf + ((size_t)gk * H + h) * 256 + kslot[it] * 8
                : krot + (size_t)gk * 64 + (kslot[it] - 16) * 8;
            kreg[it] = *reinterpret_cast<const short8*>(src);
        }
        #pragma unroll
        for (int it = 0; it < 2; ++it)
            #pragma unroll
            for (int j = 0; j < 8; ++j)
                vreg[it][j] = *reinterpret_cast<const unsigned*>(
                    kvbf + ((size_t)(t * 64 + vt8[it] * 8 + j) * H + h) * 256 + 128 + 2 * vd2[it]);
    };
    auto write_lds = [&]() {
        #pragma unroll
        for (int it = 0; it < 6; ++it) {
            int sl = (kslot[it] & 24) | ((kslot[it] ^ kt[it]) & 7);
            *reinterpret_cast<short8*>(&Ks[kt[it] * 192 + sl * 8]) = kreg[it];
        }
        #pragma unroll
        for (int it = 0; it < 2; ++it) {
            uint4 lo, hi;
            unsigned* lp = &lo.x; unsigned* hp = &hi.x;
            #pragma unroll
            for (int p2 = 0; p2 < 4; ++p2) {
                unsigned a = vreg[it][2 * p2], b = vreg[it][2 * p2 + 1];
                lp[p2] = (a & 0xffffu) | (b << 16);
                hp[p2] = (a >> 16) | (b & 0xffff0000u);
            }
            int sl = (vt8[it] ^ vd2[it]) & 7;
            *reinterpret_cast<uint4*>(&Vt[vd2[it] * 64 + sl * 8]) = lo;
            *reinterpret_cast<uint4*>(&Vt[(64 + vd2[it]) * 64 + sl * 8]) = hi;
        }
    };

    float m_run[4] = {-1e30f, -1e30f, -1e30f, -1e30f};
    float l_run[4] = {0.f, 0.f, 0.f, 0.f};
    f32x4 acc_o[8];
    #pragma unroll
    for (int i = 0; i < 8; ++i) acc_o[i] = (f32x4){0.f, 0.f, 0.f, 0.f};

    issue_loads(t0);
    for (int t = t0; t < t1; ++t) {
        __syncthreads();               // all waves done reading prev tile
        write_lds();                   // implicit vmcnt wait on this tile's loads
        __syncthreads();               // tile ready
        if (t + 1 < t1) issue_loads(t + 1);   // hides under compute

        // QK^T: 4 col-tiles x 6 k-steps
        f32x4 sacc[4];
        #pragma unroll
        for (int ct = 0; ct < 4; ++ct) sacc[ct] = (f32x4){0.f, 0.f, 0.f, 0.f};
        __builtin_amdgcn_s_setprio(1);
        #pragma unroll
        for (int ks = 0; ks < 6; ++ks) {
            #pragma unroll
            for (int ct = 0; ct < 4; ++ct) {
                int key = ct * 16 + colk;
                int slotIdx = ks * 4 + grp;
                int sl = (slotIdx & 24) | ((slotIdx ^ key) & 7);
                short8 b = *reinterpret_cast<const short8*>(&Ks[key * 192 + sl * 8]);
                sacc[ct] = __builtin_amdgcn_mfma_f32_16x16x32_bf16(qreg[ks], b, sacc[ct], 0, 0, 0);
            }
        }
        __builtin_amdgcn_s_setprio(0);

        // gated online softmax
        const bool lastTile = (t == qb);
        float sv[4][4], lmax[4];
        bool need = false;
        #pragma unroll
        for (int r = 0; r < 4; ++r) {
            int qg = s0 + w * 16 + grp * 4 + r;
            #pragma unroll
            for (int ct = 0; ct < 4; ++ct) {
                float val = sacc[ct][r];
                if (lastTile) {
                    int key = t * 64 + ct * 16 + colk;
                    val = (key <= qg) ? val : -1e30f;
                }
                sv[r][ct] = val;
            }
            lmax[r] = fmaxf(fmaxf(sv[r][0], sv[r][1]), fmaxf(sv[r][2], sv[r][3]));
            need = need || (lmax[r] > m_run[r] + 8.f);
        }
        if (__any((int)need)) {
            #pragma unroll
            for (int r = 0; r < 4; ++r) {
                float m = lmax[r];
                m = fmaxf(m, __shfl_xor(m, 1));
                m = fmaxf(m, __shfl_xor(m, 2));
                m = fmaxf(m, __shfl_xor(m, 4));
                m = fmaxf(m, __shfl_xor(m, 8));
                float mnew = fmaxf(m_run[r], m);
                float f = __expf(m_run[r] - mnew);
                m_run[r] = mnew;
                l_run[r] *= f;
                #pragma unroll
                for (int ct = 0; ct < 8; ++ct) acc_o[ct][r] *= f;
            }
        }
        #pragma unroll
        for (int r = 0; r < 4; ++r) {
            int prow = w * 16 + grp * 4 + r;
            float psum = 0.f;
            #pragma unroll
            for (int ct = 0; ct < 4; ++ct) {
                float pz = __expf(sv[r][ct] - m_run[r]);
                int col = ct * 16 + colk;
                Ps[prow * 64 + ((((col >> 3) ^ prow) & 7) << 3) + (col & 7)] = f2bf(pz);
                psum += pz;
            }
            l_run[r] += psum;
        }

        // PV: O[16x128] += P[16x64] @ V[64x128]  (Ps rows wave-private)
        __builtin_amdgcn_s_setprio(1);
        #pragma unroll
        for (int ks2 = 0; ks2 < 2; ++ks2) {
            int prow = w * 16 + colk;
            int psl = ((ks2 * 4 + grp) ^ prow) & 7;
            short8 pa = *reinterpret_cast<const short8*>(&Ps[prow * 64 + psl * 8]);
            #pragma unroll
            for (int ct = 0; ct < 8; ++ct) {
                int cc = ct * 16 + colk;
                int phys = (cc >> 1) + (cc & 1) * 64;
                int vsl = ((ks2 * 4 + grp) ^ phys) & 7;
                short8 vb = *reinterpret_cast<const short8*>(&Vt[phys * 64 + vsl * 8]);
                acc_o[ct] = __builtin_amdgcn_mfma_f32_16x16x32_bf16(pa, vb, acc_o[ct], 0, 0, 0);
            }
        }
        __builtin_amdgcn_s_setprio(0);
    }

    // epilogue
    #pragma unroll
    for (int r = 0; r < 4; ++r) {
        float l = l_run[r];
        l += __shfl_xor(l, 1);
        l += __shfl_xor(l, 2);
        l += __shfl_xor(l, 4);
        l += __shfl_xor(l, 8);
        int rloc = w * 16 + grp * 4 + r;
        int grow = s0 + rloc;
        if (S == 1) {
            float invl = 1.0f / l;
            #pragma unroll
            for (int ct = 0; ct < 8; ++ct)
                outb[(size_t)grow * 2048 + h * 128 + ct * 16 + colk] = f2bf(acc_o[ct][r] * invl);
        } else {
            if (colk == 0) {
                partML[(size_t)slotId * 128 + rloc * 2]     = m_run[r];
                partML[(size_t)slotId * 128 + rloc * 2 + 1] = l;
            }
            float* pa = partAcc + (size_t)slotId * 8192 + rloc * 128;
            #pragma unroll
            for (int ct = 0; ct < 8; ++ct)
                pa[ct * 16 + colk] = acc_o[ct][r];
        }
    }
}

// ---------------- combine partial chunks ----------------
__global__ __launch_bounds__(256) void attn_combine(
    const float* __restrict__ partAcc, const float* __restrict__ partML,
    u16* __restrict__ outb)
{
    const int bid = blockIdx.x;                 // 384
    const int xcd = bid & 7, s2 = bid >> 3;     // 0..47
    const int h = xcd + 8 * (s2 / 24);
    const int qb = 8 + s2 % 24;
    int S, poff;
    if (qb < 16)      { S = 2; poff = (qb - 8) * 2; }
    else if (qb < 24) { S = 3; poff = 16 + (qb - 16) * 3; }
    else              { S = 4; poff = 40 + (qb - 24) * 4; }
    const int base = h * 72 + poff;
    const int tid = threadIdx.x;
    const int row = tid >> 2, seg = (tid & 3) * 32;

    float mv[4], lv[4];
    float m_g = -1e30f;
    #pragma unroll
    for (int s = 0; s < 4; ++s) {
        bool ok = (s < S);
        mv[s] = ok ? partML[(size_t)(base + s) * 128 + row * 2]     : -1e30f;
        lv[s] = ok ? partML[(size_t)(base + s) * 128 + row * 2 + 1] : 0.f;
        m_g = fmaxf(m_g, mv[s]);
    }
    float l_g = 0.f, wq[4];
    #pragma unroll
    for (int s = 0; s < 4; ++s) { wq[s] = __expf(mv[s] - m_g); l_g += wq[s] * lv[s]; }
    float inv = 1.f / l_g;
    u16* orow = outb + (size_t)(qb * 64 + row) * 2048 + h * 128 + seg;
    #pragma unroll
    for (int i = 0; i < 8; ++i) {
        float4 o = make_float4(0.f, 0.f, 0.f, 0.f);
        #pragma unroll
        for (int s = 0; s < 4; ++s) {
            if (s < S) {
                float4 a = *reinterpret_cast<const float4*>(
                    partAcc + (size_t)(base + s) * 8192 + row * 128 + seg + i * 4);
                o.x += wq[s] * a.x; o.y += wq[s] * a.y;
                o.z += wq[s] * a.z; o.w += wq[s] * a.w;
            }
        }
        uint2 pk;
        pk.x = pack2(o.x * inv, o.y * inv);
        pk.y = pack2(o.z * inv, o.w * inv);
        *reinterpret_cast<uint2*>(orow + i * 4) = pk;
    }
}

extern "C" void kernel_launch(void* const* d_in, const int* in_sizes, int n_in,
                              void* d_out, int out_size, void* d_ws, size_t ws_size,
                              hipStream_t stream)
{
    (void)in_sizes; (void)n_in; (void)out_size; (void)ws_size;
    const float* x         = (const float*)d_in[0];
    const float* Wq_down   = (const float*)d_in[1];
    const float* q_norm_w  = (const float*)d_in[2];
    const float* Wq_up     = (const float*)d_in[3];
    const float* Wkv_down  = (const float*)d_in[4];
    const float* kv_norm_w = (const float*)d_in[5];
    const float* Wkv_up    = (const float*)d_in[6];
    const float* Wo        = (const float*)d_in[7];
    float* out = (float*)d_out;

    char* p = (char*)d_ws;
    u16* BtF     = (u16*)p;   p += (size_t)2176 * 2048 * 2;   // fused [Wqd|Wkvd]^T
    u16* Wkvu_t  = (u16*)p;   p += (size_t)4096 * 512  * 2;
    u16* Wo_t    = (u16*)p;   p += (size_t)2048 * 2048 * 2;
    u16* qbuf    = (u16*)p;   p += (size_t)2048 * 3072 * 2;
    u16* ckvb    = (u16*)p;   p += (size_t)2048 * 512  * 2;
    u16* kvbf    = (u16*)p;   p += (size_t)2048 * 4096 * 2;
    u16* krotb   = (u16*)p;   p += (size_t)2048 * 64   * 2;
    // dead-by-attn pool (reused for partials): xb, Wqu_t, fC, qdb  (41.4 MB >= 38.4 MB)
    u16* xb      = (u16*)p;   p += (size_t)2048 * 2048 * 2;
    u16* Wqu_t   = (u16*)p;   p += (size_t)3072 * 1536 * 2;
    float* fC    = (float*)p; p += (size_t)2048 * 2112 * 4;
    u16* qdb     = (u16*)p;   p += (size_t)2048 * 1536 * 2;
    u16* attb    = (u16*)BtF;                     // aliases BtF (dead before attn)
    float* partAcc = (float*)xb;                  // 1152*8192 f32
    float* partML  = partAcc + (size_t)1152 * 8192;

    dim3 blk(256);
    cast_f32_bf16<<<2048, blk, 0, stream>>>(x, xb);
    tcast_all<<<3776, blk, 0, stream>>>(Wq_down, Wkv_down, Wq_up, Wkv_up, Wo,
                                        BtF, Wqu_t, Wkvu_t, Wo_t);

    gemm_bf16<false><<<dim3(17, 16), blk, 0, stream>>>(xb, BtF, fC, 2048, 2112, 2048);
    rmsnorm_bf16<<<2048, blk, 0, stream>>>(fC, q_norm_w, qdb, 2112, 1536, 1536);
    gemm_bf16<true><<<dim3(24, 16), blk, 0, stream>>>(qdb, Wqu_t, qbuf, 2048, 3072, 1536);
    rmsnorm_bf16<<<2048, blk, 0, stream>>>(fC + 1536, kv_norm_w, ckvb, 2112, 512, 512);
    gemm_bf16<true><<<dim3(32, 16), blk, 0, stream>>>(ckvb, Wkvu_t, kvbf, 2048, 4096, 512);
    rope_bf16<<<2048, blk, 0, stream>>>(qbuf, fC + 2048, 2112, krotb);

    attn_chunk<<<dim3(1280), blk, 0, stream>>>(qbuf, kvbf, krotb, attb, partAcc, partML);
    attn_combine<<<dim3(384), blk, 0, stream>>>(partAcc, partML, attb);

    gemm_bf16<false><<<dim3(16, 16), blk, 0, stream>>>(attb, Wo_t, out, 2048, 2048, 2048);
}

// Round 7
// 236.400 us; speedup vs baseline: 14.5768x; 1.0073x over previous
//
#include <hip/hip_runtime.h>
#include <hip/hip_bf16.h>
#include <cstddef>

#define H 16
#define DN 128
#define DR 64
#define DV 128
#define QLR 1536
#define KVLR 512
#define HID 2048
#define SLEN 2048
#define EPS 1e-6f
#define SCALE 0.08838834764831845f   /* 1/sqrt(128) */
#define QK_SCALE (0.08838834764831845f * 1.4426950408889634f)  /* SCALE * log2(e) */

typedef __attribute__((ext_vector_type(8))) short short8;
typedef __attribute__((ext_vector_type(4))) float f32x4;
typedef unsigned short u16;

__device__ __forceinline__ u16 f2bf(float f) {
    __hip_bfloat16 h = __float2bfloat16(f);
    return __builtin_bit_cast(u16, h);
}
__device__ __forceinline__ float b2f(u16 v) {
    return __bfloat162float(__builtin_bit_cast(__hip_bfloat16, v));
}
__device__ __forceinline__ unsigned pack2(float a, float b) {
    return (unsigned)f2bf(a) | ((unsigned)f2bf(b) << 16);
}

// ---------------- elementwise f32 -> bf16 cast ----------------
__global__ __launch_bounds__(256) void cast_f32_bf16(
    const float* __restrict__ in, u16* __restrict__ out)
{
    size_t base = ((size_t)blockIdx.x * 256 + threadIdx.x) * 8;
    float4 v0 = *reinterpret_cast<const float4*>(in + base);
    float4 v1 = *reinterpret_cast<const float4*>(in + base + 4);
    union { short8 s; unsigned u[4]; } p;
    p.u[0] = pack2(v0.x, v0.y); p.u[1] = pack2(v0.z, v0.w);
    p.u[2] = pack2(v1.x, v1.y); p.u[3] = pack2(v1.z, v1.w);
    *reinterpret_cast<short8*>(out + base) = p.s;
}

// ---------------- fused transpose-cast of all 5 weights ----------------
__global__ __launch_bounds__(256) void tcast_all(
    const float* __restrict__ Wqd, const float* __restrict__ Wkvd,
    const float* __restrict__ Wqu, const float* __restrict__ Wkvu,
    const float* __restrict__ Wo,
    u16* __restrict__ BtF, u16* __restrict__ Wqu_t,
    u16* __restrict__ Wkvu_t, u16* __restrict__ Wo_t)
{
    int b = blockIdx.x;
    const float* W; u16* Wt; int K, N, nx; float scale = 1.0f;
    if (b < 768)       { W = Wqd;  Wt = BtF;                          K = 2048; N = 1536; nx = 24; }
    else if (b < 1088) { b -= 768;  W = Wkvd; Wt = BtF + (size_t)1536 * 2048; K = 2048; N = 576;  nx = 10; }
    else if (b < 2240) { b -= 1088; W = Wqu;  Wt = Wqu_t;             K = 1536; N = 3072; nx = 48; scale = QK_SCALE; }
    else if (b < 2752) { b -= 2240; W = Wkvu; Wt = Wkvu_t;            K = 512;  N = 4096; nx = 64; }
    else               { b -= 2752; W = Wo;   Wt = Wo_t;              K = 2048; N = 2048; nx = 32; }
    const int bx = b % nx, by = b / nx;

    __shared__ float T[64][65];
    const int tid = threadIdx.x;
    const int n0 = bx * 64, k0 = by * 64;
    const bool inb = (n0 < N);
    {
        int r = tid >> 4, c4 = (tid & 15) * 4;
        #pragma unroll
        for (int rr = 0; rr < 4; ++rr) {
            int row = rr * 16 + r;
            float4 v = inb ? *reinterpret_cast<const float4*>(W + (size_t)(k0 + row) * N + n0 + c4)
                           : make_float4(0.f, 0.f, 0.f, 0.f);
            T[row][c4] = v.x * scale; T[row][c4 + 1] = v.y * scale;
            T[row][c4 + 2] = v.z * scale; T[row][c4 + 3] = v.w * scale;
        }
    }
    __syncthreads();
    {
        int n = tid >> 2, kq = (tid & 3) * 16;
        unsigned u[8];
        #pragma unroll
        for (int jj = 0; jj < 8; ++jj)
            u[jj] = pack2(T[kq + 2 * jj][n], T[kq + 2 * jj + 1][n]);
        u16* dst = Wt + (size_t)(n0 + n) * K + k0 + kq;
        *reinterpret_cast<uint4*>(dst)     = make_uint4(u[0], u[1], u[2], u[3]);
        *reinterpret_cast<uint4*>(dst + 8) = make_uint4(u[4], u[5], u[6], u[7]);
    }
}

// ---------------- bf16 MFMA GEMM: C[M,N] = A[M,K] @ Bt[Npad,K]^T ----------------
__device__ __forceinline__ void stage4(const char* Gb, const unsigned* srcOff,
                                       const int* ldsBase, u16* smemBuf, unsigned koff)
{
    #pragma unroll
    for (int j = 0; j < 4; ++j)
        __builtin_amdgcn_global_load_lds(
            (const __attribute__((address_space(1))) unsigned int*)(Gb + srcOff[j] + koff),
            (__attribute__((address_space(3))) unsigned int*)(smemBuf + ldsBase[j]),
            16, 0, 0);
}

template<bool BF16OUT>
__global__ __launch_bounds__(256) void gemm_bf16(
    const u16* __restrict__ A, const u16* __restrict__ Bt,
    void* __restrict__ Cv, int M, int N, int K)
{
    __shared__ u16 smem[2][8192];
    const int tid = threadIdx.x, lane = tid & 63, w = tid >> 6;

    const int nbx = gridDim.x, nby = gridDim.y;
    const int nwg = nbx * nby;
    int orig = blockIdx.y * nbx + blockIdx.x;
    int xcd = orig & 7, o8 = orig >> 3;
    int qq = nwg >> 3, rr = nwg & 7;
    int v = (xcd < rr ? xcd * (qq + 1) : rr * (qq + 1) + (xcd - rr) * qq) + o8;
    int bx = v / nby, by = v - bx * nby;
    const int m0 = by * 128, n0 = bx * 128;
    const size_t Kb = (size_t)K * 2;

    unsigned srcOff[4];
    int ldsBase[4];
    #pragma unroll
    for (int j = 0; j < 4; ++j) {
        int c = w * 4 + j;
        int o = (c & 7) * 1024 + lane * 16;
        int u = o ^ (((o >> 7) & 3) << 4);
        int row = u >> 6, kbyte = u & 63;
        srcOff[j] = (unsigned)((size_t)((c < 8 ? m0 : n0) + row) * Kb + kbyte);
        ldsBase[j] = (c < 8) ? (c * 512) : (4096 + (c - 8) * 512);
    }
    const char* Gb = (w < 2) ? (const char*)A : (const char*)Bt;

    const int wr = (w >> 1) * 64, wc = (w & 1) * 64;
    int aoff[4], boff[4];
    #pragma unroll
    for (int i = 0; i < 4; ++i) {
        int oa = (wr + i * 16 + (lane & 15)) * 64 + (lane >> 4) * 16;
        aoff[i] = oa ^ (((oa >> 7) & 3) << 4);
        int ob = (wc + i * 16 + (lane & 15)) * 64 + (lane >> 4) * 16;
        boff[i] = (ob ^ (((ob >> 7) & 3) << 4)) + 8192;
    }

    f32x4 acc[4][4];
    #pragma unroll
    for (int i = 0; i < 4; ++i)
        #pragma unroll
        for (int j = 0; j < 4; ++j) acc[i][j] = (f32x4){0.f, 0.f, 0.f, 0.f};

    const int NT = K >> 5;
    stage4(Gb, srcOff, ldsBase, &smem[0][0], 0);
    __syncthreads();
    int cur = 0;
    for (int t = 0; t < NT; ++t) {
        if (t + 1 < NT) stage4(Gb, srcOff, ldsBase, &smem[cur ^ 1][0], (unsigned)(t + 1) * 64);
        const char* base = (const char*)&smem[cur][0];
        short8 af[4], bfr[4];
        #pragma unroll
        for (int i = 0; i < 4; ++i) af[i] = *reinterpret_cast<const short8*>(base + aoff[i]);
        #pragma unroll
        for (int i = 0; i < 4; ++i) bfr[i] = *reinterpret_cast<const short8*>(base + boff[i]);
        __builtin_amdgcn_s_setprio(1);
        #pragma unroll
        for (int i = 0; i < 4; ++i)
            #pragma unroll
            for (int j = 0; j < 4; ++j)
                acc[i][j] = __builtin_amdgcn_mfma_f32_16x16x32_bf16(af[i], bfr[j], acc[i][j], 0, 0, 0);
        __builtin_amdgcn_s_setprio(0);
        __syncthreads();
        cur ^= 1;
    }

    #pragma unroll
    for (int i = 0; i < 4; ++i) {
        int grow0 = m0 + wr + i * 16 + ((lane >> 4) * 4);
        #pragma unroll
        for (int j = 0; j < 4; ++j) {
            int gcol = n0 + wc + j * 16 + (lane & 15);
            if (gcol < N) {
                #pragma unroll
                for (int r = 0; r < 4; ++r) {
                    float v2 = acc[i][j][r];
                    if (BF16OUT) ((u16*)Cv)[(size_t)(grow0 + r) * N + gcol] = f2bf(v2);
                    else         ((float*)Cv)[(size_t)(grow0 + r) * N + gcol] = v2;
                }
            }
        }
    }
}

// ---------------- fused double RMSNorm: fC rows -> qdb (1536) + ckvb (512) ----------------
__global__ __launch_bounds__(256) void rmsnorm2_bf16(
    const float* __restrict__ fC, const float* __restrict__ qw,
    const float* __restrict__ kvw, u16* __restrict__ qdb, u16* __restrict__ ckvb)
{
    const int row = blockIdx.x, tid = threadIdx.x;
    const float* p = fC + (size_t)row * 2112;
    float ssq = 0.f, ssk = 0.f;
    for (int i = tid * 4; i < 1536; i += 1024) {
        float4 v = *reinterpret_cast<const float4*>(p + i);
        ssq += v.x * v.x + v.y * v.y + v.z * v.z + v.w * v.w;
    }
    if (tid < 128) {
        float4 v = *reinterpret_cast<const float4*>(p + 1536 + tid * 4);
        ssk = v.x * v.x + v.y * v.y + v.z * v.z + v.w * v.w;
    }
    __shared__ float wsq[4], wsk[4];
    int lane = tid & 63, wv = tid >> 6;
    #pragma unroll
    for (int off = 32; off; off >>= 1) {
        ssq += __shfl_down(ssq, off);
        ssk += __shfl_down(ssk, off);
    }
    if (lane == 0) { wsq[wv] = ssq; wsk[wv] = ssk; }
    __syncthreads();
    if (tid == 0) {
        wsq[0] = rsqrtf((wsq[0] + wsq[1] + wsq[2] + wsq[3]) / 1536.f + EPS);
        wsk[0] = rsqrtf((wsk[0] + wsk[1] + wsk[2] + wsk[3]) / 512.f + EPS);
    }
    __syncthreads();
    float scq = wsq[0], sck = wsk[0];
    for (int i = tid * 4; i < 1536; i += 1024) {
        float4 v = *reinterpret_cast<const float4*>(p + i);
        float4 g = *reinterpret_cast<const float4*>(qw + i);
        *reinterpret_cast<uint2*>(qdb + (size_t)row * 1536 + i) =
            make_uint2(pack2(v.x * scq * g.x, v.y * scq * g.y),
                       pack2(v.z * scq * g.z, v.w * scq * g.w));
    }
    if (tid < 128) {
        int i = tid * 4;
        float4 v = *reinterpret_cast<const float4*>(p + 1536 + i);
        float4 g = *reinterpret_cast<const float4*>(kvw + i);
        *reinterpret_cast<uint2*>(ckvb + (size_t)row * 512 + i) =
            make_uint2(pack2(v.x * sck * g.x, v.y * sck * g.y),
                       pack2(v.z * sck * g.z, v.w * sck * g.w));
    }
}

// ---------------- RoPE in place on bf16 q + krot from f32 (strided) ----------------
__global__ __launch_bounds__(256) void rope_bf16(
    u16* __restrict__ q, const float* __restrict__ krsrc, int krStride,
    u16* __restrict__ krot)
{
    const int s = blockIdx.x, tid = threadIdx.x;
    __shared__ float cs[32], sn[32];
    if (tid < 32) {
        float inv = powf(10000.0f, -(float)tid / 32.0f);
        float ang = (float)s * inv;
        cs[tid] = cosf(ang); sn[tid] = sinf(ang);
    }
    __syncthreads();
    float ev[2], ov[2]; int hh[2], ii[2];
    #pragma unroll
    for (int it = 0; it < 2; ++it) {
        int pidx = tid + it * 256;
        int h = pidx >> 5, i = pidx & 31;
        hh[it] = h; ii[it] = i;
        const u16* base = q + (size_t)s * 3072 + h * 192 + 128;
        ev[it] = b2f(base[2 * i]); ov[it] = b2f(base[2 * i + 1]);
    }
    __syncthreads();
    #pragma unroll
    for (int it = 0; it < 2; ++it) {
        int h = hh[it], i = ii[it];
        u16* base = q + (size_t)s * 3072 + h * 192 + 128;
        base[i]      = f2bf(ev[it] * cs[i] - ov[it] * sn[i]);
        base[32 + i] = f2bf(ov[it] * cs[i] + ev[it] * sn[i]);
    }
    if (tid < 32) {
        int i = tid;
        float e = krsrc[(size_t)s * krStride + 2 * i];
        float o = krsrc[(size_t)s * krStride + 2 * i + 1];
        krot[(size_t)s * 64 + i]      = f2bf(e * cs[i] - o * sn[i]);
        krot[(size_t)s * 64 + 32 + i] = f2bf(o * cs[i] + e * sn[i]);
    }
}

// ---------------- split-K flash attention chunk kernel ----------------
// 1280 blocks, big-chunks-first XCD-mapped; 256 thr = 4 waves; KB=64/tile.
// Softmax in log2 units (Q pre-scaled by SCALE*log2e); exp2f == v_exp_f32.
__global__ __launch_bounds__(256, 2) void attn_chunk(
    const u16* __restrict__ qbf,   // [S][H][192]
    const u16* __restrict__ kvbf,  // [S][H][256]
    const u16* __restrict__ krot,  // [S][64]
    u16* __restrict__ outb,        // [S][2048]
    float* __restrict__ partAcc,   // [1152][64][128]
    float* __restrict__ partML)    // [1152][64][2]
{
    const int bid = blockIdx.x;
    const int xcd = bid & 7, slot = bid >> 3;       // slot 0..159
    const int h = xcd + 8 * (slot & 1);             // interleave heads
    const int r80 = 79 - (slot >> 1);               // big chunks first
    int qb, ch, S, poff;
    if (r80 < 8)       { qb = r80;                 ch = 0;      S = 1; poff = 0; }
    else if (r80 < 24) { int u = r80 - 8;  qb = 8 + (u >> 1);  ch = u & 1; S = 2; poff = (qb - 8) * 2 + ch; }
    else if (r80 < 48) { int u = r80 - 24; qb = 16 + u / 3;    ch = u % 3; S = 3; poff = 16 + (qb - 16) * 3 + ch; }
    else               { int u = r80 - 48; qb = 24 + (u >> 2); ch = u & 3; S = 4; poff = 40 + (qb - 24) * 4 + ch; }
    const int s0 = qb * 64;
    const int t0 = ch * 8;
    const int t1 = (t0 + 8 < qb + 1) ? (t0 + 8) : (qb + 1);
    const int slotId = h * 72 + poff;
    const int tid = threadIdx.x, lane = tid & 63, w = tid >> 6;
    const int colk = lane & 15, grp = lane >> 4, g8 = grp * 8;

    __shared__ u16 Ks[64 * 192];   // row stride 192 u16, 16B slots XOR'd by (key&7)
    __shared__ u16 Vt[128 * 64];   // phys row=(d>>1)+(d&1)*64, slots XOR'd by (phys&7)
    __shared__ u16 Ps[64 * 64];    // row stride 64 u16, slots XOR'd by (row&7)

    // Q fragments (pre-scaled by SCALE*log2e via Wq_up fold)
    short8 qreg[6];
    {
        const u16* qp = qbf + ((size_t)(s0 + w * 16 + colk) * H + h) * 192;
        #pragma unroll
        for (int ks = 0; ks < 6; ++ks)
            qreg[ks] = *reinterpret_cast<const short8*>(qp + ks * 32 + g8);
    }

    // staging geometry
    int kt[6], kslot[6];
    #pragma unroll
    for (int it = 0; it < 6; ++it) {
        int c = it * 256 + tid;
        kt[it] = c / 24; kslot[it] = c % 24;
    }
    int vd2[2], vt8[2];
    #pragma unroll
    for (int it = 0; it < 2; ++it) {
        int c = it * 256 + tid;
        vd2[it] = c & 63; vt8[it] = c >> 6;
    }

    short8 kreg[6];
    unsigned vreg[2][8];

    auto issue_loads = [&](int t) {
        #pragma unroll
        for (int it = 0; it < 6; ++it) {
            int gk = t * 64 + kt[it];
            const u16* src = (kslot[it] < 16)
                ? kvbf + ((size_t)gk * H + h) * 256 + kslot[it] * 8
                : krot + (size_t)gk * 64 + (kslot[it] - 16) * 8;
            kreg[it] = *reinterpret_cast<const short8*>(src);
        }
        #pragma unroll
        for (int it = 0; it < 2; ++it)
            #pragma unroll
            for (int j = 0; j < 8; ++j)
                vreg[it][j] = *reinterpret_cast<const unsigned*>(
                    kvbf + ((size_t)(t * 64 + vt8[it] * 8 + j) * H + h) * 256 + 128 + 2 * vd2[it]);
    };
    auto write_lds = [&]() {
        #pragma unroll
        for (int it = 0; it < 6; ++it) {
            int sl = (kslot[it] & 24) | ((kslot[it] ^ kt[it]) & 7);
            *reinterpret_cast<short8*>(&Ks[kt[it] * 192 + sl * 8]) = kreg[it];
        }
        #pragma unroll
        for (int it = 0; it < 2; ++it) {
            uint4 lo, hi;
            unsigned* lp = &lo.x; unsigned* hp = &hi.x;
            #pragma unroll
            for (int p2 = 0; p2 < 4; ++p2) {
                unsigned a = vreg[it][2 * p2], b = vreg[it][2 * p2 + 1];
                lp[p2] = (a & 0xffffu) | (b << 16);
                hp[p2] = (a >> 16) | (b & 0xffff0000u);
            }
            int sl = (vt8[it] ^ vd2[it]) & 7;
            *reinterpret_cast<uint4*>(&Vt[vd2[it] * 64 + sl * 8]) = lo;
            *reinterpret_cast<uint4*>(&Vt[(64 + vd2[it]) * 64 + sl * 8]) = hi;
        }
    };

    float m_run[4] = {-1e30f, -1e30f, -1e30f, -1e30f};
    float l_run[4] = {0.f, 0.f, 0.f, 0.f};
    f32x4 acc_o[8];
    #pragma unroll
    for (int i = 0; i < 8; ++i) acc_o[i] = (f32x4){0.f, 0.f, 0.f, 0.f};

    issue_loads(t0);
    for (int t = t0; t < t1; ++t) {
        __syncthreads();               // all waves done reading prev tile
        write_lds();                   // implicit vmcnt wait on this tile's loads
        __syncthreads();               // tile ready
        if (t + 1 < t1) issue_loads(t + 1);   // hides under compute

        // QK^T: 4 col-tiles x 6 k-steps
        f32x4 sacc[4];
        #pragma unroll
        for (int ct = 0; ct < 4; ++ct) sacc[ct] = (f32x4){0.f, 0.f, 0.f, 0.f};
        __builtin_amdgcn_s_setprio(1);
        #pragma unroll
        for (int ks = 0; ks < 6; ++ks) {
            #pragma unroll
            for (int ct = 0; ct < 4; ++ct) {
                int key = ct * 16 + colk;
                int slotIdx = ks * 4 + grp;
                int sl = (slotIdx & 24) | ((slotIdx ^ key) & 7);
                short8 b = *reinterpret_cast<const short8*>(&Ks[key * 192 + sl * 8]);
                sacc[ct] = __builtin_amdgcn_mfma_f32_16x16x32_bf16(qreg[ks], b, sacc[ct], 0, 0, 0);
            }
        }
        __builtin_amdgcn_s_setprio(0);

        // gated online softmax (log2 units)
        const bool lastTile = (t == qb);
        float sv[4][4], lmax[4];
        bool need = false;
        #pragma unroll
        for (int r = 0; r < 4; ++r) {
            int qg = s0 + w * 16 + grp * 4 + r;
            #pragma unroll
            for (int ct = 0; ct < 4; ++ct) {
                float val = sacc[ct][r];
                if (lastTile) {
                    int key = t * 64 + ct * 16 + colk;
                    val = (key <= qg) ? val : -1e30f;
                }
                sv[r][ct] = val;
            }
            lmax[r] = fmaxf(fmaxf(sv[r][0], sv[r][1]), fmaxf(sv[r][2], sv[r][3]));
            need = need || (lmax[r] > m_run[r] + 11.5f);
        }
        if (__any((int)need)) {
            #pragma unroll
            for (int r = 0; r < 4; ++r) {
                float m = lmax[r];
                m = fmaxf(m, __shfl_xor(m, 1));
                m = fmaxf(m, __shfl_xor(m, 2));
                m = fmaxf(m, __shfl_xor(m, 4));
                m = fmaxf(m, __shfl_xor(m, 8));
                float mnew = fmaxf(m_run[r], m);
                float f = exp2f(m_run[r] - mnew);
                m_run[r] = mnew;
                l_run[r] *= f;
                #pragma unroll
                for (int ct = 0; ct < 8; ++ct) acc_o[ct][r] *= f;
            }
        }
        #pragma unroll
        for (int r = 0; r < 4; ++r) {
            int prow = w * 16 + grp * 4 + r;
            float psum = 0.f;
            #pragma unroll
            for (int ct = 0; ct < 4; ++ct) {
                float pz = exp2f(sv[r][ct] - m_run[r]);
                int col = ct * 16 + colk;
                Ps[prow * 64 + ((((col >> 3) ^ prow) & 7) << 3) + (col & 7)] = f2bf(pz);
                psum += pz;
            }
            l_run[r] += psum;
        }

        // PV: O[16x128] += P[16x64] @ V[64x128]  (Ps rows wave-private)
        __builtin_amdgcn_s_setprio(1);
        #pragma unroll
        for (int ks2 = 0; ks2 < 2; ++ks2) {
            int prow = w * 16 + colk;
            int psl = ((ks2 * 4 + grp) ^ prow) & 7;
            short8 pa = *reinterpret_cast<const short8*>(&Ps[prow * 64 + psl * 8]);
            #pragma unroll
            for (int ct = 0; ct < 8; ++ct) {
                int cc = ct * 16 + colk;
                int phys = (cc >> 1) + (cc & 1) * 64;
                int vsl = ((ks2 * 4 + grp) ^ phys) & 7;
                short8 vb = *reinterpret_cast<const short8*>(&Vt[phys * 64 + vsl * 8]);
                acc_o[ct] = __builtin_amdgcn_mfma_f32_16x16x32_bf16(pa, vb, acc_o[ct], 0, 0, 0);
            }
        }
        __builtin_amdgcn_s_setprio(0);
    }

    // epilogue
    #pragma unroll
    for (int r = 0; r < 4; ++r) {
        float l = l_run[r];
        l += __shfl_xor(l, 1);
        l += __shfl_xor(l, 2);
        l += __shfl_xor(l, 4);
        l += __shfl_xor(l, 8);
        int rloc = w * 16 + grp * 4 + r;
        int grow = s0 + rloc;
        if (S == 1) {
            float invl = 1.0f / l;
            #pragma unroll
            for (int ct = 0; ct < 8; ++ct)
                outb[(size_t)grow * 2048 + h * 128 + ct * 16 + colk] = f2bf(acc_o[ct][r] * invl);
        } else {
            if (colk == 0) {
                partML[(size_t)slotId * 128 + rloc * 2]     = m_run[r];
                partML[(size_t)slotId * 128 + rloc * 2 + 1] = l;
            }
            float* pa = partAcc + (size_t)slotId * 8192 + rloc * 128;
            #pragma unroll
            for (int ct = 0; ct < 8; ++ct)
                pa[ct * 16 + colk] = acc_o[ct][r];
        }
    }
}

// ---------------- combine partial chunks (log2-unit m) ----------------
__global__ __launch_bounds__(256) void attn_combine(
    const float* __restrict__ partAcc, const float* __restrict__ partML,
    u16* __restrict__ outb)
{
    const int bid = blockIdx.x;                 // 384
    const int xcd = bid & 7, s2 = bid >> 3;     // 0..47
    const int h = xcd + 8 * (s2 / 24);
    const int qb = 8 + s2 % 24;
    int S, poff;
    if (qb < 16)      { S = 2; poff = (qb - 8) * 2; }
    else if (qb < 24) { S = 3; poff = 16 + (qb - 16) * 3; }
    else              { S = 4; poff = 40 + (qb - 24) * 4; }
    const int base = h * 72 + poff;
    const int tid = threadIdx.x;
    const int row = tid >> 2, seg = (tid & 3) * 32;

    float mv[4], lv[4];
    float m_g = -1e30f;
    #pragma unroll
    for (int s = 0; s < 4; ++s) {
        bool ok = (s < S);
        mv[s] = ok ? partML[(size_t)(base + s) * 128 + row * 2]     : -1e30f;
        lv[s] = ok ? partML[(size_t)(base + s) * 128 + row * 2 + 1] : 0.f;
        m_g = fmaxf(m_g, mv[s]);
    }
    float l_g = 0.f, wq[4];
    #pragma unroll
    for (int s = 0; s < 4; ++s) { wq[s] = exp2f(mv[s] - m_g); l_g += wq[s] * lv[s]; }
    float inv = 1.f / l_g;
    u16* orow = outb + (size_t)(qb * 64 + row) * 2048 + h * 128 + seg;
    #pragma unroll
    for (int i = 0; i < 8; ++i) {
        float4 o = make_float4(0.f, 0.f, 0.f, 0.f);
        #pragma unroll
        for (int s = 0; s < 4; ++s) {
            if (s < S) {
                float4 a = *reinterpret_cast<const float4*>(
                    partAcc + (size_t)(base + s) * 8192 + row * 128 + seg + i * 4);
                o.x += wq[s] * a.x; o.y += wq[s] * a.y;
                o.z += wq[s] * a.z; o.w += wq[s] * a.w;
            }
        }
        uint2 pk;
        pk.x = pack2(o.x * inv, o.y * inv);
        pk.y = pack2(o.z * inv, o.w * inv);
        *reinterpret_cast<uint2*>(orow + i * 4) = pk;
    }
}

extern "C" void kernel_launch(void* const* d_in, const int* in_sizes, int n_in,
                              void* d_out, int out_size, void* d_ws, size_t ws_size,
                              hipStream_t stream)
{
    (void)in_sizes; (void)n_in; (void)out_size; (void)ws_size;
    const float* x         = (const float*)d_in[0];
    const float* Wq_down   = (const float*)d_in[1];
    const float* q_norm_w  = (const float*)d_in[2];
    const float* Wq_up     = (const float*)d_in[3];
    const float* Wkv_down  = (const float*)d_in[4];
    const float* kv_norm_w = (const float*)d_in[5];
    const float* Wkv_up    = (const float*)d_in[6];
    const float* Wo        = (const float*)d_in[7];
    float* out = (float*)d_out;

    char* p = (char*)d_ws;
    u16* BtF     = (u16*)p;   p += (size_t)2176 * 2048 * 2;   // fused [Wqd|Wkvd]^T
    u16* Wkvu_t  = (u16*)p;   p += (size_t)4096 * 512  * 2;
    u16* Wo_t    = (u16*)p;   p += (size_t)2048 * 2048 * 2;
    u16* qbuf    = (u16*)p;   p += (size_t)2048 * 3072 * 2;
    u16* ckvb    = (u16*)p;   p += (size_t)2048 * 512  * 2;
    u16* kvbf    = (u16*)p;   p += (size_t)2048 * 4096 * 2;
    u16* krotb   = (u16*)p;   p += (size_t)2048 * 64   * 2;
    // dead-by-attn pool (reused for partials): xb, Wqu_t, fC, qdb
    u16* xb      = (u16*)p;   p += (size_t)2048 * 2048 * 2;
    u16* Wqu_t   = (u16*)p;   p += (size_t)3072 * 1536 * 2;
    float* fC    = (float*)p; p += (size_t)2048 * 2112 * 4;
    u16* qdb     = (u16*)p;   p += (size_t)2048 * 1536 * 2;
    u16* attb    = (u16*)BtF;                     // aliases BtF (dead before attn)
    float* partAcc = (float*)xb;                  // 1152*8192 f32
    float* partML  = partAcc + (size_t)1152 * 8192;

    dim3 blk(256);
    cast_f32_bf16<<<2048, blk, 0, stream>>>(x, xb);
    tcast_all<<<3776, blk, 0, stream>>>(Wq_down, Wkv_down, Wq_up, Wkv_up, Wo,
                                        BtF, Wqu_t, Wkvu_t, Wo_t);

    gemm_bf16<false><<<dim3(17, 16), blk, 0, stream>>>(xb, BtF, fC, 2048, 2112, 2048);
    rmsnorm2_bf16<<<2048, blk, 0, stream>>>(fC, q_norm_w, kv_norm_w, qdb, ckvb);
    gemm_bf16<true><<<dim3(24, 16), blk, 0, stream>>>(qdb, Wqu_t, qbuf, 2048, 3072, 1536);
    gemm_bf16<true><<<dim3(32, 16), blk, 0, stream>>>(ckvb, Wkvu_t, kvbf, 2048, 4096, 512);
    rope_bf16<<<2048, blk, 0, stream>>>(qbuf, fC + 2048, 2112, krotb);

    attn_chunk<<<dim3(1280), blk, 0, stream>>>(qbuf, kvbf, krotb, attb, partAcc, partML);
    attn_combine<<<dim3(384), blk, 0, stream>>>(partAcc, partML, attb);

    gemm_bf16<false><<<dim3(16, 16), blk, 0, stream>>>(attb, Wo_t, out, 2048, 2048, 2048);
}